// Round 6
// baseline (181.746 us; speedup 1.0000x reference)
//
#include <hip/hip_runtime.h>
#include <hip/hip_bf16.h>

// CrossAttention: b=4, n=1024, qs=256, heads=8, dim_head=64, bottleneck=40.
// Attention = full 8192x8192 softmax-attention per batch over D=64.
//
// R19:
//  - attn: occupancy restructure. R5 counters: MFMA busy 45% + VALU 42%
//    at 73us = pipes serialized; 2 lockstep waves/SIMD (148 regs -> 256
//    granule). Split 4-mt waves into 2-mt waves: 512-thr blocks, 8 waves
//    (2 q-groups x 4 kv-quarters), qf 32->16, oacc 64->32 AGPR (~100
//    combined), launch_bounds(512,4) -> 4 waves/SIMD. unroll 1 protects
//    the 128-reg cap. setprio REVERTED (R18: -3us, T5 needs role-split).
//  - conv/qkv/out: frozen R17.
//
// Workspace: Q|K_sw|V_sw 12MB | Opart 16MB | psum 256KB | WOB 512KB |
//            W1B 128KB | W2B 384KB ~ 29.3MB.

#define B_    4
#define H_    8
#define NSEQ  1024
#define SEQ   8192        // H_*NSEQ
#define DH    64
#define QS    256
#define INNER 512
#define QSCALE 0.18033688011112042f   // (1/sqrt(64)) * log2(e)

#define KVSW_BATCH 524288             // elems per batch in K_sw / V_sw
#define OPHALF (2097152)              // B_*SEQ*DH

typedef __bf16 bf16x8 __attribute__((ext_vector_type(8)));
typedef float floatx4 __attribute__((ext_vector_type(4)));

// ---------------- kernel 0: weight -> bf16 hi/lo fragment conversion ----------------
// grid 80, 256 thr. blocks [0,16): w1cat (256x128, cols 120-127 zero);
// [16,64): w2 per proj (K 40->64 zero-pad, N=512); [64,80): wo (as R16).
__global__ __launch_bounds__(256) void conv_kernel(
    const float* __restrict__ wq1, const float* __restrict__ wk1,
    const float* __restrict__ wv1,
    const float* __restrict__ wq2, const float* __restrict__ wk2,
    const float* __restrict__ wv2,
    const float* __restrict__ wo,
    __hip_bfloat16* __restrict__ W1BH, __hip_bfloat16* __restrict__ W1BL,
    __hip_bfloat16* __restrict__ W2BH, __hip_bfloat16* __restrict__ W2BL,
    __hip_bfloat16* __restrict__ WOBH, __hip_bfloat16* __restrict__ WOBL)
{
  const int tid = threadIdx.x;
  const int blk = blockIdx.x;

  if (blk < 16) {
    // ---- W1B: task t -> n = t&127, kq = t>>7 (kc = kq>>2, q = kq&3)
    const int t  = blk * 256 + tid;
    const int n  = t & 127;
    const int kq = t >> 7;
    const int kc = kq >> 2, q = kq & 3;
    const float* src; int col;
    if (n < 40)       { src = wq1; col = n; }
    else if (n < 80)  { src = wk1; col = n - 40; }
    else if (n < 120) { src = wv1; col = n - 80; }
    else              { src = nullptr; col = 0; }
    bf16x8 hv, lv;
    #pragma unroll
    for (int j = 0; j < 8; ++j) {
      const int k = kc * 32 + q * 8 + j;
      const float v = src ? src[k * 40 + col] : 0.f;
      const __bf16 h16 = (__bf16)v;
      hv[j] = h16; lv[j] = (__bf16)(v - (float)h16);
    }
    const size_t off = (((size_t)(n >> 4) * 8 + kc) * 64 + (n & 15) + 16 * q) * 8;
    *(bf16x8*)(W1BH + off) = hv;
    *(bf16x8*)(W1BL + off) = lv;
  } else if (blk < 64) {
    // ---- W2B: task t -> n = t&511, r = t>>9 (p = r>>3, kc = (r>>2)&1, q = r&3)
    const int t  = (blk - 16) * 256 + tid;
    const int n  = t & 511;
    const int r  = t >> 9;                    // [0,24)
    const int p  = r >> 3;
    const int kq = r & 7;
    const int kc = kq >> 2, q = kq & 3;
    const float* w2 = (p == 0) ? wq2 : (p == 1) ? wk2 : wv2;
    bf16x8 hv, lv;
    #pragma unroll
    for (int j = 0; j < 8; ++j) {
      const int k = kc * 32 + q * 8 + j;
      const float v = (k < 40) ? w2[(size_t)k * 512 + n] : 0.f;
      const __bf16 h16 = (__bf16)v;
      hv[j] = h16; lv[j] = (__bf16)(v - (float)h16);
    }
    const size_t off = ((((size_t)p * 32 + (n >> 4)) * 2 + kc) * 64 + (n & 15) + 16 * q) * 8;
    *(bf16x8*)(W2BH + off) = hv;
    *(bf16x8*)(W2BL + off) = lv;
  } else {
    // ---- WOB: identical math to R16 (harness-verified), re-strided to 256 thr.
    const int cid = blk - 64;                 // [0,16)
    const int t4  = (cid * 256 + tid) * 4;
    const int n   = t4 & 255;
    const int k8  = t4 >> 8;
    float4 rr[8];
    #pragma unroll
    for (int kk = 0; kk < 8; ++kk)
      rr[kk] = *(const float4*)(wo + (size_t)(k8 * 8 + kk) * QS + n);
    const int kc = k8 >> 2, qq = k8 & 3;
    #pragma unroll
    for (int nn = 0; nn < 4; ++nn) {
      const int nc = n + nn;
      const int l  = (nc & 15) + 16 * qq;
      const size_t off = ((size_t)((nc >> 4) * 16 + kc) * 64 + l) * 8;
      bf16x8 hv, lv;
      #pragma unroll
      for (int kk = 0; kk < 8; ++kk) {
        const float v = (nn == 0) ? rr[kk].x : (nn == 1) ? rr[kk].y
                      : (nn == 2) ? rr[kk].z : rr[kk].w;
        const __bf16 h16 = (__bf16)v;
        hv[kk] = h16;
        lv[kk] = (__bf16)(v - (float)h16);
      }
      *(bf16x8*)(WOBH + off) = hv;
      *(bf16x8*)(WOBL + off) = lv;
    }
  }
}

// ---------------- kernel 1: QKV projections, MFMA (frozen R17) ----------------
// grid 256 (b*64 + nblk), 512 thr (8 waves), 16 x-rows per block, all 3 proj.
__global__ __launch_bounds__(512) void qkv_kernel(
    const float* __restrict__ x,
    const __hip_bfloat16* __restrict__ W1BH, const __hip_bfloat16* __restrict__ W1BL,
    const __hip_bfloat16* __restrict__ W2BH, const __hip_bfloat16* __restrict__ W2BL,
    __hip_bfloat16* __restrict__ Qg, __hip_bfloat16* __restrict__ KSg,
    __hip_bfloat16* __restrict__ VSg)
{
  const int tid  = threadIdx.x;
  const int b    = blockIdx.x >> 6;
  const int nblk = blockIdx.x & 63;
  const int n0   = nblk << 4;
  const int wave = tid >> 6;
  const int lane = tid & 63;
  const int m    = lane & 15;     // A-frag row / D col-part
  const int q    = lane >> 4;     // k-subgroup / D row-quad

  __shared__ __align__(16) float xs[16][260];
  __shared__ __align__(16) float tb32[16][140];
  __shared__ __align__(16) __hip_bfloat16 qb[8320];    // [16][520]
  __shared__ __align__(16) __hip_bfloat16 kb[8320];    // [16][520]
  __shared__ __align__(16) __hip_bfloat16 vb[10240];   // [512][20]

  // stage x tile: 1024 float4 tasks, 2 per thread
  #pragma unroll
  for (int j = 0; j < 2; ++j) {
    const int i  = tid + j * 512;
    const int r  = i >> 6;
    const int c4 = (i & 63) << 2;
    *(float4*)(&xs[r][c4]) =
        *(const float4*)(x + ((size_t)b * NSEQ + n0 + r) * QS + c4);
  }
  __syncthreads();

  // ---- build x A-frags (hi/lo), all 8 K-chunks: row m, k = kc*32+q*8+j
  bf16x8 xh[8], xl[8];
  #pragma unroll
  for (int kc = 0; kc < 8; ++kc) {
    const float4 f0 = *(const float4*)(&xs[m][kc * 32 + q * 8]);
    const float4 f1 = *(const float4*)(&xs[m][kc * 32 + q * 8 + 4]);
    float v[8] = {f0.x, f0.y, f0.z, f0.w, f1.x, f1.y, f1.z, f1.w};
    #pragma unroll
    for (int j = 0; j < 8; ++j) {
      const __bf16 h16 = (__bf16)v[j];
      xh[kc][j] = h16;
      xl[kc][j] = (__bf16)(v[j] - (float)h16);
    }
  }

  // ---- stage 1: wave w owns cat n-tile w. 24 MFMA (3-chain hi/lo).
  {
    floatx4 hh = (floatx4){0.f, 0.f, 0.f, 0.f};
    floatx4 hl = (floatx4){0.f, 0.f, 0.f, 0.f};
    floatx4 lh = (floatx4){0.f, 0.f, 0.f, 0.f};
    const __hip_bfloat16* w1h = W1BH + ((size_t)wave * 8 * 64 + lane) * 8;
    const __hip_bfloat16* w1l = W1BL + ((size_t)wave * 8 * 64 + lane) * 8;
    #pragma unroll
    for (int kc = 0; kc < 8; ++kc) {
      const bf16x8 bh = *(const bf16x8*)(w1h + kc * 512);
      const bf16x8 bl = *(const bf16x8*)(w1l + kc * 512);
      hh = __builtin_amdgcn_mfma_f32_16x16x32_bf16(xh[kc], bh, hh, 0, 0, 0);
      hl = __builtin_amdgcn_mfma_f32_16x16x32_bf16(xh[kc], bl, hl, 0, 0, 0);
      lh = __builtin_amdgcn_mfma_f32_16x16x32_bf16(xl[kc], bh, lh, 0, 0, 0);
    }
    const int n1 = wave * 16 + m;   // cat col (D col = lane&15)
    #pragma unroll
    for (int r = 0; r < 4; ++r) {
      float d = (hh[r] + hl[r]) + lh[r];
      if (n1 >= 40 && n1 < 80) d = d / (1.f + __expf(-d));   // SiLU on K path
      tb32[q * 4 + r][n1] = d;       // D row = q*4+r
    }
  }
  __syncthreads();

  // ---- stage 2: per proj p (compile-time), wave covers n-tiles wave*4+i.
  #pragma unroll
  for (int p = 0; p < 3; ++p) {
    bf16x8 a2h[2], a2l[2];
    {
      const float4 g0 = *(const float4*)(&tb32[m][p * 40 + q * 8]);
      const float4 g1 = *(const float4*)(&tb32[m][p * 40 + q * 8 + 4]);
      float v[8] = {g0.x, g0.y, g0.z, g0.w, g1.x, g1.y, g1.z, g1.w};
      #pragma unroll
      for (int j = 0; j < 8; ++j) {
        const __bf16 h16 = (__bf16)v[j];
        a2h[0][j] = h16;
        a2l[0][j] = (__bf16)(v[j] - (float)h16);
      }
    }
    if (q == 0) {
      const float4 g0 = *(const float4*)(&tb32[m][p * 40 + 32]);
      const float4 g1 = *(const float4*)(&tb32[m][p * 40 + 36]);
      float v[8] = {g0.x, g0.y, g0.z, g0.w, g1.x, g1.y, g1.z, g1.w};
      #pragma unroll
      for (int j = 0; j < 8; ++j) {
        const __bf16 h16 = (__bf16)v[j];
        a2h[1][j] = h16;
        a2l[1][j] = (__bf16)(v[j] - (float)h16);
      }
    } else {
      #pragma unroll
      for (int j = 0; j < 8; ++j) { a2h[1][j] = (__bf16)0.f; a2l[1][j] = (__bf16)0.f; }
    }

    #pragma unroll
    for (int i = 0; i < 4; ++i) {
      const int nt = wave * 4 + i;
      floatx4 sHH = (floatx4){0.f, 0.f, 0.f, 0.f};
      floatx4 sHL = (floatx4){0.f, 0.f, 0.f, 0.f};
      floatx4 sLH = (floatx4){0.f, 0.f, 0.f, 0.f};
      #pragma unroll
      for (int kc = 0; kc < 2; ++kc) {
        const size_t boff = (((size_t)(p * 32 + nt) * 2 + kc) * 64 + lane) * 8;
        const bf16x8 bh = *(const bf16x8*)(W2BH + boff);
        const bf16x8 bl = *(const bf16x8*)(W2BL + boff);
        sHH = __builtin_amdgcn_mfma_f32_16x16x32_bf16(a2h[kc], bh, sHH, 0, 0, 0);
        sHL = __builtin_amdgcn_mfma_f32_16x16x32_bf16(a2h[kc], bl, sHL, 0, 0, 0);
        sLH = __builtin_amdgcn_mfma_f32_16x16x32_bf16(a2l[kc], bh, sLH, 0, 0, 0);
      }
      const int nn = nt * 16 + m;    // output col [0,512)
      #pragma unroll
      for (int r = 0; r < 4; ++r) {
        const int row = q * 4 + r;
        const float d = (sHH[r] + sHL[r]) + sLH[r];
        if (p == 0)      qb[row * 520 + nn] = __float2bfloat16(d * QSCALE);
        else if (p == 1) kb[row * 520 + nn] = __float2bfloat16(d);
        else             vb[nn * 20 + row]  = __float2bfloat16(d);
      }
    }
  }
  __syncthreads();

  // ---- Q write: 1024 float4 tasks, 2 per thread (R15-identical) ----
  #pragma unroll
  for (int j = 0; j < 2; ++j) {
    const int i  = tid + j * 512;
    const int h  = i >> 7;
    const int r  = (i >> 3) & 15;
    const int d8 = i & 7;
    *(float4*)(Qg + ((size_t)b * SEQ + h * NSEQ + n0 + r) * DH + d8 * 8) =
        *(const float4*)(&qb[r * 520 + h * 64 + d8 * 8]);
  }
  // ---- K_sw write: 1024 float4 tasks, 2 per thread (R15-identical) ----
  #pragma unroll
  for (int j = 0; j < 2; ++j) {
    const int i    = tid + j * 512;
    const int h    = i >> 7;
    const int ks2  = (i >> 6) & 1;
    const int quad = (i >> 4) & 3;
    const int r    = i & 15;
    const int ln   = quad * 16 + r;
    const size_t dst = (size_t)b * KVSW_BATCH
        + ((size_t)((h * 64 + nblk) * 2 + ks2) * 64 + ln) * 8;
    *(float4*)(KSg + dst) = *(const float4*)(&kb[r * 520 + h * 64 + ks2 * 32 + quad * 8]);
  }
  // ---- V_sw write: 2048 uint2 tasks, 4 per thread (R15-identical) ----
  {
    const int st  = nblk & 1;
    const int p32 = nblk >> 1;
    #pragma unroll
    for (int pass = 0; pass < 4; ++pass) {
      const int i   = tid + pass * 512;
      const int h   = i >> 8;
      const int dnt = (i >> 6) & 3;
      const int dm  = (i >> 2) & 15;
      const int rg  = i & 3;
      const int ln  = rg * 16 + dm;
      const size_t dst = (size_t)b * KVSW_BATCH
          + ((size_t)((h * 32 + p32) * 4 + dnt) * 64 + ln) * 8 + st * 4;
      *(uint2*)(VSg + dst) = *(const uint2*)(&vb[(h * 64 + dnt * 16 + dm) * 20 + rg * 4]);
    }
  }
}

// ---------------- kernel 2: attention — 8 waves x (2 q-rows-of-16, kv quarter) ----------------
// 512 thr: wave = qg*4 + kvq (qg in [0,2): 32 q-rows; kvq in [0,4): 1024 kv).
// Per-wave loop body identical to R13 with mt bound 4 -> 2. ~100 combined
// regs -> launch_bounds(512,4) -> 4 waves/SIMD (was 2 lockstep).
struct PairBuf {
  bf16x8 k[2][2];   // [strip][k-span]
  bf16x8 v[4];      // [d-tile]
};

__global__ __launch_bounds__(512, 4) void attn_kernel(
    const __hip_bfloat16* __restrict__ Qg,
    const __hip_bfloat16* __restrict__ KSg,
    const __hip_bfloat16* __restrict__ VSg,
    float* __restrict__ OPg,       // [2][B_][SEQ][DH]
    float* __restrict__ PSg)       // [2][B_][SEQ]
{
  __shared__ float Osh[8][16][68];
  __shared__ float psums[8][32];

  const int tid  = threadIdx.x;
  const int wave = tid >> 6;       // [0,8)
  const int lane = tid & 63;
  const int lrow = lane & 15;
  const int quad = lane >> 4;
  const int kvq  = wave & 3;       // kv quarter within the half
  const int qg   = wave >> 2;      // q group: rows qg*32 .. qg*32+31

  const int xcd   = blockIdx.x & 7;
  const int idx   = blockIdx.x >> 3;       // [0,128)
  const int b     = xcd >> 1;
  const int half  = idx & 1;
  const int qtile = (xcd & 1) * 64 + (idx >> 1);
  const int qbase = qtile * 64;

  const __hip_bfloat16* Qb  = Qg + ((size_t)b * SEQ + qbase + qg * 32) * DH;
  const __hip_bfloat16* kp0 = KSg + (size_t)b * KVSW_BATCH + half * 262144
                              + (size_t)kvq * 65536 + lane * 8;
  const __hip_bfloat16* vp0 = VSg + (size_t)b * KVSW_BATCH + half * 262144
                              + (size_t)kvq * 65536 + lane * 8;

  bf16x8 qf[2][2];
  #pragma unroll
  for (int mt = 0; mt < 2; ++mt)
    #pragma unroll
    for (int s = 0; s < 2; ++s)
      qf[mt][s] = *(const bf16x8*)(Qb + (mt * 16 + lrow) * DH + s * 32 + quad * 8);

  floatx4 oacc[2][4];   // [mt][dnt] — 32 acc regs
  #pragma unroll
  for (int mt = 0; mt < 2; ++mt)
    #pragma unroll
    for (int dnt = 0; dnt < 4; ++dnt)
      oacc[mt][dnt] = (floatx4){0.f, 0.f, 0.f, 0.f};
  float psum[2] = {0.f, 0.f};

  #pragma unroll 1
  for (int pair = 0; pair < 32; ++pair) {
    PairBuf pb;
    const __hip_bfloat16* kp = kp0 + pair * 2048;
    pb.k[0][0] = *(const bf16x8*)(kp);
    pb.k[0][1] = *(const bf16x8*)(kp + 512);
    pb.k[1][0] = *(const bf16x8*)(kp + 1024);
    pb.k[1][1] = *(const bf16x8*)(kp + 1536);
    const __hip_bfloat16* vp = vp0 + pair * 2048;
    #pragma unroll
    for (int dnt = 0; dnt < 4; ++dnt)
      pb.v[dnt] = *(const bf16x8*)(vp + dnt * 512);

    #pragma unroll
    for (int mt = 0; mt < 2; ++mt) {
      floatx4 s0 = (floatx4){0.f, 0.f, 0.f, 0.f};
      floatx4 s1 = (floatx4){0.f, 0.f, 0.f, 0.f};
      s0 = __builtin_amdgcn_mfma_f32_16x16x32_bf16(pb.k[0][0], qf[mt][0], s0, 0, 0, 0);
      s0 = __builtin_amdgcn_mfma_f32_16x16x32_bf16(pb.k[0][1], qf[mt][1], s0, 0, 0, 0);
      s1 = __builtin_amdgcn_mfma_f32_16x16x32_bf16(pb.k[1][0], qf[mt][0], s1, 0, 0, 0);
      s1 = __builtin_amdgcn_mfma_f32_16x16x32_bf16(pb.k[1][1], qf[mt][1], s1, 0, 0, 0);
      float p[8];
      #pragma unroll
      for (int r = 0; r < 4; ++r) {
        p[r]     = __builtin_amdgcn_exp2f(s0[r]);
        p[4 + r] = __builtin_amdgcn_exp2f(s1[r]);
      }
      psum[mt] += ((p[0] + p[1]) + (p[2] + p[3])) + ((p[4] + p[5]) + (p[6] + p[7]));
      bf16x8 pa;
      #pragma unroll
      for (int j = 0; j < 8; ++j) pa[j] = (__bf16)p[j];
      #pragma unroll
      for (int dnt = 0; dnt < 4; ++dnt)
        oacc[mt][dnt] = __builtin_amdgcn_mfma_f32_16x16x32_bf16(pa, pb.v[dnt], oacc[mt][dnt], 0, 0, 0);
    }
  }

  #pragma unroll
  for (int mt = 0; mt < 2; ++mt) {
    float s = psum[mt];
    s += __shfl_xor(s, 16, 64);
    s += __shfl_xor(s, 32, 64);
    psum[mt] = s;
  }
  if (quad == 0) {
    #pragma unroll
    for (int mt = 0; mt < 2; ++mt)
      psums[wave][mt * 16 + lrow] = psum[mt];
  }

  const size_t opbase = ((size_t)half * B_ + b) * SEQ + qbase;

  #pragma unroll
  for (int mt = 0; mt < 2; ++mt) {
    #pragma unroll
    for (int dnt = 0; dnt < 4; ++dnt)
      #pragma unroll
      for (int r = 0; r < 4; ++r)
        Osh[wave][quad * 4 + r][dnt * 16 + lrow] = oacc[mt][dnt][r];
    __syncthreads();

    {
      const int g   = tid >> 8;          // q group [0,2)
      const int q16 = (tid >> 4) & 15;   // row within 16
      const int d0  = (tid & 15) * 4;
      float4 a0 = *(const float4*)(&Osh[g * 4 + 0][q16][d0]);
      float4 a1 = *(const float4*)(&Osh[g * 4 + 1][q16][d0]);
      float4 a2 = *(const float4*)(&Osh[g * 4 + 2][q16][d0]);
      float4 a3 = *(const float4*)(&Osh[g * 4 + 3][q16][d0]);
      float4 res;
      res.x = (a0.x + a1.x) + (a2.x + a3.x);
      res.y = (a0.y + a1.y) + (a2.y + a3.y);
      res.z = (a0.z + a1.z) + (a2.z + a3.z);
      res.w = (a0.w + a1.w) + (a2.w + a3.w);
      *(float4*)(OPg + (opbase + g * 32 + mt * 16 + q16) * DH + d0) = res;
    }
    if (mt == 0 && tid < 64) {
      const int g = tid >> 5, rr = tid & 31;
      const float tot = (psums[g * 4 + 0][rr] + psums[g * 4 + 1][rr])
                      + (psums[g * 4 + 2][rr] + psums[g * 4 + 3][rr]);
      PSg[opbase + tid] = tot;
    }
    __syncthreads();
  }
}

// ---------------- kernel 3: out = merge(Opart)/denom @ wo + bo — MFMA (frozen R16) ----------------
__global__ __launch_bounds__(256, 1) void out_kernel(
    const float* __restrict__ OPg, const float* __restrict__ PSg,
    const __hip_bfloat16* __restrict__ WOBH, const __hip_bfloat16* __restrict__ WOBL,
    const float* __restrict__ bo, float* __restrict__ out)
{
  __shared__ __align__(16) __hip_bfloat16 apH[8192];   // [kc][lane][8]
  __shared__ __align__(16) __hip_bfloat16 apL[8192];
  __shared__ float invs[16][8];

  const int tid  = threadIdx.x;
  const int b    = blockIdx.x >> 6;
  const int n0   = (blockIdx.x & 63) << 4;
  const int lane = tid & 63;
  const int wave = tid >> 6;

  if (tid < 128) {
    const int r = tid >> 3, h = tid & 7;
    const size_t row = (size_t)b * SEQ + h * NSEQ + n0 + r;
    invs[r][h] = 1.0f / (PSg[row] + PSg[(size_t)B_ * SEQ + row]);
  }
  __syncthreads();

  // ---- phase 1: merge halves + normalize -> hi/lo A-frag pack.
  {
    const int m   = tid & 15;
    const int q   = (tid >> 4) & 3;
    const int kc0 = tid >> 6;
    #pragma unroll
    for (int pss = 0; pss < 4; ++pss) {
      const int kc = kc0 + pss * 4;
      const int h  = kc >> 1;
      const int dh = (q + 4 * (kc & 1)) * 8;
      const size_t idx = (((size_t)b * H_ + h) * NSEQ + n0 + m) * DH + dh;
      const float4 a0 = *(const float4*)(OPg + idx);
      const float4 a1 = *(const float4*)(OPg + idx + 4);
      const float4 b0 = *(const float4*)(OPg + OPHALF + idx);
      const float4 b1 = *(const float4*)(OPg + OPHALF + idx + 4);
      const float inv = invs[m][h];
      float v[8];
      v[0] = (a0.x + b0.x) * inv; v[1] = (a0.y + b0.y) * inv;
      v[2] = (a0.z + b0.z) * inv; v[3] = (a0.w + b0.w) * inv;
      v[4] = (a1.x + b1.x) * inv; v[5] = (a1.y + b1.y) * inv;
      v[6] = (a1.z + b1.z) * inv; v[7] = (a1.w + b1.w) * inv;
      bf16x8 hv, lv;
      #pragma unroll
      for (int j = 0; j < 8; ++j) {
        const __bf16 h16 = (__bf16)v[j];
        hv[j] = h16;
        lv[j] = (__bf16)(v[j] - (float)h16);
      }
      const int off = (kc * 64 + (m + 16 * q)) * 8;
      *(bf16x8*)(apH + off) = hv;
      *(bf16x8*)(apL + off) = lv;
    }
  }
  __syncthreads();

  // ---- phase 2: MFMA. A-frags (all 16 kc, hi+lo) -> 128 VGPR, B from L2.
  bf16x8 ah[16], al[16];
  #pragma unroll
  for (int kc = 0; kc < 16; ++kc) {
    ah[kc] = *(const bf16x8*)(apH + (kc * 64 + lane) * 8);
    al[kc] = *(const bf16x8*)(apL + (kc * 64 + lane) * 8);
  }

  const int colq = lane & 15;
  const int quad = lane >> 4;

  #pragma unroll
  for (int nt4 = 0; nt4 < 4; ++nt4) {
    const int nt = nt4 * 4 + wave;
    const __hip_bfloat16* wbh = WOBH + ((size_t)nt * 16 * 64 + lane) * 8;
    const __hip_bfloat16* wbl = WOBL + ((size_t)nt * 16 * 64 + lane) * 8;
    floatx4 aHH = (floatx4){0.f, 0.f, 0.f, 0.f};
    floatx4 aHL = (floatx4){0.f, 0.f, 0.f, 0.f};
    floatx4 aLH = (floatx4){0.f, 0.f, 0.f, 0.f};
    #pragma unroll
    for (int kg = 0; kg < 4; ++kg) {
      bf16x8 bh[4], bl[4];
      #pragma unroll
      for (int j = 0; j < 4; ++j) {
        bh[j] = *(const bf16x8*)(wbh + (kg * 4 + j) * 512);
        bl[j] = *(const bf16x8*)(wbl + (kg * 4 + j) * 512);
      }
      #pragma unroll
      for (int j = 0; j < 4; ++j) {
        const int kc = kg * 4 + j;
        aHH = __builtin_amdgcn_mfma_f32_16x16x32_bf16(ah[kc], bh[j], aHH, 0, 0, 0);
        aHL = __builtin_amdgcn_mfma_f32_16x16x32_bf16(ah[kc], bl[j], aHL, 0, 0, 0);
        aLH = __builtin_amdgcn_mfma_f32_16x16x32_bf16(al[kc], bh[j], aLH, 0, 0, 0);
      }
    }
    const int n  = nt * 16 + colq;
    const float bv = bo[n];
    #pragma unroll
    for (int r = 0; r < 4; ++r) {
      const int mm = quad * 4 + r;
      out[((size_t)b * NSEQ + n0 + mm) * QS + n] =
          ((aHH[r] + aHL[r]) + aLH[r]) + bv;
    }
  }
}

extern "C" void kernel_launch(void* const* d_in, const int* in_sizes, int n_in,
                              void* d_out, int out_size, void* d_ws, size_t ws_size,
                              hipStream_t stream) {
  const float* x   = (const float*)d_in[0];
  const float* wq1 = (const float*)d_in[1];
  const float* wq2 = (const float*)d_in[2];
  const float* wk1 = (const float*)d_in[3];
  const float* wk2 = (const float*)d_in[4];
  const float* wv1 = (const float*)d_in[5];
  const float* wv2 = (const float*)d_in[6];
  const float* wo  = (const float*)d_in[7];
  const float* bo  = (const float*)d_in[8];
  float* out = (float*)d_out;

  __hip_bfloat16* Qg  = (__hip_bfloat16*)d_ws;
  __hip_bfloat16* KSg = Qg + (size_t)B_ * SEQ * DH;
  __hip_bfloat16* VSg = KSg + (size_t)B_ * KVSW_BATCH;
  float*          OPg = (float*)(VSg + (size_t)B_ * KVSW_BATCH);   // [2][B_][SEQ][DH]
  float*          PSg = OPg + 2 * (size_t)B_ * SEQ * DH;           // [2][B_][SEQ]
  __hip_bfloat16* WOBH = (__hip_bfloat16*)(PSg + 2 * (size_t)B_ * SEQ);
  __hip_bfloat16* WOBL = WOBH + (size_t)INNER * QS;                // 131072
  __hip_bfloat16* W1BH = WOBL + (size_t)INNER * QS;
  __hip_bfloat16* W1BL = W1BH + 32768;
  __hip_bfloat16* W2BH = W1BL + 32768;
  __hip_bfloat16* W2BL = W2BH + 98304;

  conv_kernel<<<80, 256, 0, stream>>>(wq1, wk1, wv1, wq2, wk2, wv2, wo,
                                      W1BH, W1BL, W2BH, W2BL, WOBH, WOBL);
  qkv_kernel<<<256, 512, 0, stream>>>(x, W1BH, W1BL, W2BH, W2BL, Qg, KSg, VSg);
  attn_kernel<<<1024, 512, 0, stream>>>(Qg, KSg, VSg, OPg, PSg);
  out_kernel<<<256, 256, 0, stream>>>(OPg, PSg, WOBH, WOBL, bo, out);
}

// Round 8
// 170.540 us; speedup vs baseline: 1.0657x; 1.0657x over previous
//
#include <hip/hip_runtime.h>
#include <hip/hip_bf16.h>

// CrossAttention: b=4, n=1024, qs=256, heads=8, dim_head=64, bottleneck=40.
// Attention = full 8192x8192 softmax-attention per batch over D=64.
//
// R21:
//  - attn: R13 core loop FROZEN (4 attempts at >2 waves/SIMD all lost:
//    R14 spill, R18 setprio, R19 split, R20 asm NaN). Structural change
//    only: kv-half split removed. 512 blocks x 512 thr (8 waves = 8 kv
//    eighths, per-wave work byte-identical to R13). Osh merge now 8-way.
//    Opart written ONCE (16->8MB), PSg single.
//  - out: merge removed (single OPg/PSg read, no OPHALF).
//  - conv/qkv: frozen R17. Workspace 29.3 -> ~21MB (less harness reset).
//
// Workspace: Q|K_sw|V_sw 12MB | Opart 8MB | psum 128KB | WOB 512KB |
//            W1B 128KB | W2B 384KB ~ 21MB.

#define B_    4
#define H_    8
#define NSEQ  1024
#define SEQ   8192        // H_*NSEQ
#define DH    64
#define QS    256
#define INNER 512
#define QSCALE 0.18033688011112042f   // (1/sqrt(64)) * log2(e)

#define KVSW_BATCH 524288             // elems per batch in K_sw / V_sw

typedef __bf16 bf16x8 __attribute__((ext_vector_type(8)));
typedef float floatx4 __attribute__((ext_vector_type(4)));

// ---------------- kernel 0: weight -> bf16 hi/lo fragment conversion (frozen R17) ----------------
__global__ __launch_bounds__(256) void conv_kernel(
    const float* __restrict__ wq1, const float* __restrict__ wk1,
    const float* __restrict__ wv1,
    const float* __restrict__ wq2, const float* __restrict__ wk2,
    const float* __restrict__ wv2,
    const float* __restrict__ wo,
    __hip_bfloat16* __restrict__ W1BH, __hip_bfloat16* __restrict__ W1BL,
    __hip_bfloat16* __restrict__ W2BH, __hip_bfloat16* __restrict__ W2BL,
    __hip_bfloat16* __restrict__ WOBH, __hip_bfloat16* __restrict__ WOBL)
{
  const int tid = threadIdx.x;
  const int blk = blockIdx.x;

  if (blk < 16) {
    const int t  = blk * 256 + tid;
    const int n  = t & 127;
    const int kq = t >> 7;
    const int kc = kq >> 2, q = kq & 3;
    const float* src; int col;
    if (n < 40)       { src = wq1; col = n; }
    else if (n < 80)  { src = wk1; col = n - 40; }
    else if (n < 120) { src = wv1; col = n - 80; }
    else              { src = nullptr; col = 0; }
    bf16x8 hv, lv;
    #pragma unroll
    for (int j = 0; j < 8; ++j) {
      const int k = kc * 32 + q * 8 + j;
      const float v = src ? src[k * 40 + col] : 0.f;
      const __bf16 h16 = (__bf16)v;
      hv[j] = h16; lv[j] = (__bf16)(v - (float)h16);
    }
    const size_t off = (((size_t)(n >> 4) * 8 + kc) * 64 + (n & 15) + 16 * q) * 8;
    *(bf16x8*)(W1BH + off) = hv;
    *(bf16x8*)(W1BL + off) = lv;
  } else if (blk < 64) {
    const int t  = (blk - 16) * 256 + tid;
    const int n  = t & 511;
    const int r  = t >> 9;                    // [0,24)
    const int p  = r >> 3;
    const int kq = r & 7;
    const int kc = kq >> 2, q = kq & 3;
    const float* w2 = (p == 0) ? wq2 : (p == 1) ? wk2 : wv2;
    bf16x8 hv, lv;
    #pragma unroll
    for (int j = 0; j < 8; ++j) {
      const int k = kc * 32 + q * 8 + j;
      const float v = (k < 40) ? w2[(size_t)k * 512 + n] : 0.f;
      const __bf16 h16 = (__bf16)v;
      hv[j] = h16; lv[j] = (__bf16)(v - (float)h16);
    }
    const size_t off = ((((size_t)p * 32 + (n >> 4)) * 2 + kc) * 64 + (n & 15) + 16 * q) * 8;
    *(bf16x8*)(W2BH + off) = hv;
    *(bf16x8*)(W2BL + off) = lv;
  } else {
    const int cid = blk - 64;                 // [0,16)
    const int t4  = (cid * 256 + tid) * 4;
    const int n   = t4 & 255;
    const int k8  = t4 >> 8;
    float4 rr[8];
    #pragma unroll
    for (int kk = 0; kk < 8; ++kk)
      rr[kk] = *(const float4*)(wo + (size_t)(k8 * 8 + kk) * QS + n);
    const int kc = k8 >> 2, qq = k8 & 3;
    #pragma unroll
    for (int nn = 0; nn < 4; ++nn) {
      const int nc = n + nn;
      const int l  = (nc & 15) + 16 * qq;
      const size_t off = ((size_t)((nc >> 4) * 16 + kc) * 64 + l) * 8;
      bf16x8 hv, lv;
      #pragma unroll
      for (int kk = 0; kk < 8; ++kk) {
        const float v = (nn == 0) ? rr[kk].x : (nn == 1) ? rr[kk].y
                      : (nn == 2) ? rr[kk].z : rr[kk].w;
        const __bf16 h16 = (__bf16)v;
        hv[kk] = h16;
        lv[kk] = (__bf16)(v - (float)h16);
      }
      *(bf16x8*)(WOBH + off) = hv;
      *(bf16x8*)(WOBL + off) = lv;
    }
  }
}

// ---------------- kernel 1: QKV projections, MFMA (frozen R17) ----------------
__global__ __launch_bounds__(512) void qkv_kernel(
    const float* __restrict__ x,
    const __hip_bfloat16* __restrict__ W1BH, const __hip_bfloat16* __restrict__ W1BL,
    const __hip_bfloat16* __restrict__ W2BH, const __hip_bfloat16* __restrict__ W2BL,
    __hip_bfloat16* __restrict__ Qg, __hip_bfloat16* __restrict__ KSg,
    __hip_bfloat16* __restrict__ VSg)
{
  const int tid  = threadIdx.x;
  const int b    = blockIdx.x >> 6;
  const int nblk = blockIdx.x & 63;
  const int n0   = nblk << 4;
  const int wave = tid >> 6;
  const int lane = tid & 63;
  const int m    = lane & 15;     // A-frag row / D col-part
  const int q    = lane >> 4;     // k-subgroup / D row-quad

  __shared__ __align__(16) float xs[16][260];
  __shared__ __align__(16) float tb32[16][140];
  __shared__ __align__(16) __hip_bfloat16 qb[8320];    // [16][520]
  __shared__ __align__(16) __hip_bfloat16 kb[8320];    // [16][520]
  __shared__ __align__(16) __hip_bfloat16 vb[10240];   // [512][20]

  #pragma unroll
  for (int j = 0; j < 2; ++j) {
    const int i  = tid + j * 512;
    const int r  = i >> 6;
    const int c4 = (i & 63) << 2;
    *(float4*)(&xs[r][c4]) =
        *(const float4*)(x + ((size_t)b * NSEQ + n0 + r) * QS + c4);
  }
  __syncthreads();

  bf16x8 xh[8], xl[8];
  #pragma unroll
  for (int kc = 0; kc < 8; ++kc) {
    const float4 f0 = *(const float4*)(&xs[m][kc * 32 + q * 8]);
    const float4 f1 = *(const float4*)(&xs[m][kc * 32 + q * 8 + 4]);
    float v[8] = {f0.x, f0.y, f0.z, f0.w, f1.x, f1.y, f1.z, f1.w};
    #pragma unroll
    for (int j = 0; j < 8; ++j) {
      const __bf16 h16 = (__bf16)v[j];
      xh[kc][j] = h16;
      xl[kc][j] = (__bf16)(v[j] - (float)h16);
    }
  }

  {
    floatx4 hh = (floatx4){0.f, 0.f, 0.f, 0.f};
    floatx4 hl = (floatx4){0.f, 0.f, 0.f, 0.f};
    floatx4 lh = (floatx4){0.f, 0.f, 0.f, 0.f};
    const __hip_bfloat16* w1h = W1BH + ((size_t)wave * 8 * 64 + lane) * 8;
    const __hip_bfloat16* w1l = W1BL + ((size_t)wave * 8 * 64 + lane) * 8;
    #pragma unroll
    for (int kc = 0; kc < 8; ++kc) {
      const bf16x8 bh = *(const bf16x8*)(w1h + kc * 512);
      const bf16x8 bl = *(const bf16x8*)(w1l + kc * 512);
      hh = __builtin_amdgcn_mfma_f32_16x16x32_bf16(xh[kc], bh, hh, 0, 0, 0);
      hl = __builtin_amdgcn_mfma_f32_16x16x32_bf16(xh[kc], bl, hl, 0, 0, 0);
      lh = __builtin_amdgcn_mfma_f32_16x16x32_bf16(xl[kc], bh, lh, 0, 0, 0);
    }
    const int n1 = wave * 16 + m;   // cat col (D col = lane&15)
    #pragma unroll
    for (int r = 0; r < 4; ++r) {
      float d = (hh[r] + hl[r]) + lh[r];
      if (n1 >= 40 && n1 < 80) d = d / (1.f + __expf(-d));   // SiLU on K path
      tb32[q * 4 + r][n1] = d;       // D row = q*4+r
    }
  }
  __syncthreads();

  #pragma unroll
  for (int p = 0; p < 3; ++p) {
    bf16x8 a2h[2], a2l[2];
    {
      const float4 g0 = *(const float4*)(&tb32[m][p * 40 + q * 8]);
      const float4 g1 = *(const float4*)(&tb32[m][p * 40 + q * 8 + 4]);
      float v[8] = {g0.x, g0.y, g0.z, g0.w, g1.x, g1.y, g1.z, g1.w};
      #pragma unroll
      for (int j = 0; j < 8; ++j) {
        const __bf16 h16 = (__bf16)v[j];
        a2h[0][j] = h16;
        a2l[0][j] = (__bf16)(v[j] - (float)h16);
      }
    }
    if (q == 0) {
      const float4 g0 = *(const float4*)(&tb32[m][p * 40 + 32]);
      const float4 g1 = *(const float4*)(&tb32[m][p * 40 + 36]);
      float v[8] = {g0.x, g0.y, g0.z, g0.w, g1.x, g1.y, g1.z, g1.w};
      #pragma unroll
      for (int j = 0; j < 8; ++j) {
        const __bf16 h16 = (__bf16)v[j];
        a2h[1][j] = h16;
        a2l[1][j] = (__bf16)(v[j] - (float)h16);
      }
    } else {
      #pragma unroll
      for (int j = 0; j < 8; ++j) { a2h[1][j] = (__bf16)0.f; a2l[1][j] = (__bf16)0.f; }
    }

    #pragma unroll
    for (int i = 0; i < 4; ++i) {
      const int nt = wave * 4 + i;
      floatx4 sHH = (floatx4){0.f, 0.f, 0.f, 0.f};
      floatx4 sHL = (floatx4){0.f, 0.f, 0.f, 0.f};
      floatx4 sLH = (floatx4){0.f, 0.f, 0.f, 0.f};
      #pragma unroll
      for (int kc = 0; kc < 2; ++kc) {
        const size_t boff = (((size_t)(p * 32 + nt) * 2 + kc) * 64 + lane) * 8;
        const bf16x8 bh = *(const bf16x8*)(W2BH + boff);
        const bf16x8 bl = *(const bf16x8*)(W2BL + boff);
        sHH = __builtin_amdgcn_mfma_f32_16x16x32_bf16(a2h[kc], bh, sHH, 0, 0, 0);
        sHL = __builtin_amdgcn_mfma_f32_16x16x32_bf16(a2h[kc], bl, sHL, 0, 0, 0);
        sLH = __builtin_amdgcn_mfma_f32_16x16x32_bf16(a2l[kc], bh, sLH, 0, 0, 0);
      }
      const int nn = nt * 16 + m;    // output col [0,512)
      #pragma unroll
      for (int r = 0; r < 4; ++r) {
        const int row = q * 4 + r;
        const float d = (sHH[r] + sHL[r]) + sLH[r];
        if (p == 0)      qb[row * 520 + nn] = __float2bfloat16(d * QSCALE);
        else if (p == 1) kb[row * 520 + nn] = __float2bfloat16(d);
        else             vb[nn * 20 + row]  = __float2bfloat16(d);
      }
    }
  }
  __syncthreads();

  #pragma unroll
  for (int j = 0; j < 2; ++j) {
    const int i  = tid + j * 512;
    const int h  = i >> 7;
    const int r  = (i >> 3) & 15;
    const int d8 = i & 7;
    *(float4*)(Qg + ((size_t)b * SEQ + h * NSEQ + n0 + r) * DH + d8 * 8) =
        *(const float4*)(&qb[r * 520 + h * 64 + d8 * 8]);
  }
  #pragma unroll
  for (int j = 0; j < 2; ++j) {
    const int i    = tid + j * 512;
    const int h    = i >> 7;
    const int ks2  = (i >> 6) & 1;
    const int quad = (i >> 4) & 3;
    const int r    = i & 15;
    const int ln   = quad * 16 + r;
    const size_t dst = (size_t)b * KVSW_BATCH
        + ((size_t)((h * 64 + nblk) * 2 + ks2) * 64 + ln) * 8;
    *(float4*)(KSg + dst) = *(const float4*)(&kb[r * 520 + h * 64 + ks2 * 32 + quad * 8]);
  }
  {
    const int st  = nblk & 1;
    const int p32 = nblk >> 1;
    #pragma unroll
    for (int pass = 0; pass < 4; ++pass) {
      const int i   = tid + pass * 512;
      const int h   = i >> 8;
      const int dnt = (i >> 6) & 3;
      const int dm  = (i >> 2) & 15;
      const int rg  = i & 3;
      const int ln  = rg * 16 + dm;
      const size_t dst = (size_t)b * KVSW_BATCH
          + ((size_t)((h * 32 + p32) * 4 + dnt) * 64 + ln) * 8 + st * 4;
      *(uint2*)(VSg + dst) = *(const uint2*)(&vb[(h * 64 + dnt * 16 + dm) * 20 + rg * 4]);
    }
  }
}

// ---------------- kernel 2: attention — full kv per block, 8 waves ----------------
// 512 blocks (xcd = blk&7 -> b = xcd>>1, qtile = (xcd&1)*64 + blk>>3),
// 512 thr: wave = kv eighth (1024 kv rows each — per-wave work identical
// to R13). Osh merge is 8-way; Opart/PSg written once (no halves).
struct PairBuf {
  bf16x8 k[2][2];   // [strip][k-span]
  bf16x8 v[4];      // [d-tile]
};

__global__ __launch_bounds__(512, 2) void attn_kernel(
    const __hip_bfloat16* __restrict__ Qg,
    const __hip_bfloat16* __restrict__ KSg,
    const __hip_bfloat16* __restrict__ VSg,
    float* __restrict__ OPg,       // [B_][SEQ][DH]
    float* __restrict__ PSg)       // [B_][SEQ]
{
  __shared__ float Osh[8][16][68];
  __shared__ float psums[8][64];

  const int tid  = threadIdx.x;
  const int wave = tid >> 6;       // [0,8) — kv eighth
  const int lane = tid & 63;
  const int lrow = lane & 15;
  const int quad = lane >> 4;

  const int xcd   = blockIdx.x & 7;
  const int idx   = blockIdx.x >> 3;       // [0,64)
  const int b     = xcd >> 1;
  const int qtile = (xcd & 1) * 64 + idx;  // [0,128)
  const int qbase = qtile * 64;

  const __hip_bfloat16* Qb  = Qg + ((size_t)b * SEQ + qbase) * DH;
  const __hip_bfloat16* kp0 = KSg + (size_t)b * KVSW_BATCH
                              + (size_t)wave * 65536 + lane * 8;
  const __hip_bfloat16* vp0 = VSg + (size_t)b * KVSW_BATCH
                              + (size_t)wave * 65536 + lane * 8;

  bf16x8 qf[4][2];
  #pragma unroll
  for (int mt = 0; mt < 4; ++mt)
    #pragma unroll
    for (int s = 0; s < 2; ++s)
      qf[mt][s] = *(const bf16x8*)(Qb + (mt * 16 + lrow) * DH + s * 32 + quad * 8);

  floatx4 oacc[4][4];   // [mt][dnt] — 64 acc regs (unified budget)
  #pragma unroll
  for (int mt = 0; mt < 4; ++mt)
    #pragma unroll
    for (int dnt = 0; dnt < 4; ++dnt)
      oacc[mt][dnt] = (floatx4){0.f, 0.f, 0.f, 0.f};
  float psum[4] = {0.f, 0.f, 0.f, 0.f};

  #pragma unroll 2
  for (int pair = 0; pair < 32; ++pair) {
    PairBuf pb;
    const __hip_bfloat16* kp = kp0 + pair * 2048;
    pb.k[0][0] = *(const bf16x8*)(kp);
    pb.k[0][1] = *(const bf16x8*)(kp + 512);
    pb.k[1][0] = *(const bf16x8*)(kp + 1024);
    pb.k[1][1] = *(const bf16x8*)(kp + 1536);
    const __hip_bfloat16* vp = vp0 + pair * 2048;
    #pragma unroll
    for (int dnt = 0; dnt < 4; ++dnt)
      pb.v[dnt] = *(const bf16x8*)(vp + dnt * 512);

    #pragma unroll
    for (int mt = 0; mt < 4; ++mt) {
      floatx4 s0 = (floatx4){0.f, 0.f, 0.f, 0.f};
      floatx4 s1 = (floatx4){0.f, 0.f, 0.f, 0.f};
      s0 = __builtin_amdgcn_mfma_f32_16x16x32_bf16(pb.k[0][0], qf[mt][0], s0, 0, 0, 0);
      s0 = __builtin_amdgcn_mfma_f32_16x16x32_bf16(pb.k[0][1], qf[mt][1], s0, 0, 0, 0);
      s1 = __builtin_amdgcn_mfma_f32_16x16x32_bf16(pb.k[1][0], qf[mt][0], s1, 0, 0, 0);
      s1 = __builtin_amdgcn_mfma_f32_16x16x32_bf16(pb.k[1][1], qf[mt][1], s1, 0, 0, 0);
      float p[8];
      #pragma unroll
      for (int r = 0; r < 4; ++r) {
        p[r]     = __builtin_amdgcn_exp2f(s0[r]);
        p[4 + r] = __builtin_amdgcn_exp2f(s1[r]);
      }
      psum[mt] += ((p[0] + p[1]) + (p[2] + p[3])) + ((p[4] + p[5]) + (p[6] + p[7]));
      bf16x8 pa;
      #pragma unroll
      for (int j = 0; j < 8; ++j) pa[j] = (__bf16)p[j];
      #pragma unroll
      for (int dnt = 0; dnt < 4; ++dnt)
        oacc[mt][dnt] = __builtin_amdgcn_mfma_f32_16x16x32_bf16(pa, pb.v[dnt], oacc[mt][dnt], 0, 0, 0);
    }
  }

  #pragma unroll
  for (int mt = 0; mt < 4; ++mt) {
    float s = psum[mt];
    s += __shfl_xor(s, 16, 64);
    s += __shfl_xor(s, 32, 64);
    psum[mt] = s;
  }
  if (quad == 0) {
    #pragma unroll
    for (int mt = 0; mt < 4; ++mt)
      psums[wave][mt * 16 + lrow] = psum[mt];
  }

  const size_t opbase = (size_t)b * SEQ + qbase;

  #pragma unroll
  for (int mt = 0; mt < 4; ++mt) {
    #pragma unroll
    for (int dnt = 0; dnt < 4; ++dnt)
      #pragma unroll
      for (int r = 0; r < 4; ++r)
        Osh[wave][quad * 4 + r][dnt * 16 + lrow] = oacc[mt][dnt][r];
    __syncthreads();

    if (tid < 256) {
      const int q16 = tid >> 4;
      const int d0  = (tid & 15) * 4;
      float4 a0 = *(const float4*)(&Osh[0][q16][d0]);
      float4 a1 = *(const float4*)(&Osh[1][q16][d0]);
      float4 a2 = *(const float4*)(&Osh[2][q16][d0]);
      float4 a3 = *(const float4*)(&Osh[3][q16][d0]);
      float4 a4 = *(const float4*)(&Osh[4][q16][d0]);
      float4 a5 = *(const float4*)(&Osh[5][q16][d0]);
      float4 a6 = *(const float4*)(&Osh[6][q16][d0]);
      float4 a7 = *(const float4*)(&Osh[7][q16][d0]);
      float4 res;
      res.x = ((a0.x + a1.x) + (a2.x + a3.x)) + ((a4.x + a5.x) + (a6.x + a7.x));
      res.y = ((a0.y + a1.y) + (a2.y + a3.y)) + ((a4.y + a5.y) + (a6.y + a7.y));
      res.z = ((a0.z + a1.z) + (a2.z + a3.z)) + ((a4.z + a5.z) + (a6.z + a7.z));
      res.w = ((a0.w + a1.w) + (a2.w + a3.w)) + ((a4.w + a5.w) + (a6.w + a7.w));
      *(float4*)(OPg + (opbase + mt * 16 + q16) * DH + d0) = res;
    }
    if (mt == 0 && tid < 64) {
      const float tot = ((psums[0][tid] + psums[1][tid]) + (psums[2][tid] + psums[3][tid]))
                      + ((psums[4][tid] + psums[5][tid]) + (psums[6][tid] + psums[7][tid]));
      PSg[opbase + tid] = tot;
    }
    __syncthreads();
  }
}

// ---------------- kernel 3: out = (Opart/denom) @ wo + bo — MFMA (merge removed) ----------------
__global__ __launch_bounds__(256, 1) void out_kernel(
    const float* __restrict__ OPg, const float* __restrict__ PSg,
    const __hip_bfloat16* __restrict__ WOBH, const __hip_bfloat16* __restrict__ WOBL,
    const float* __restrict__ bo, float* __restrict__ out)
{
  __shared__ __align__(16) __hip_bfloat16 apH[8192];   // [kc][lane][8]
  __shared__ __align__(16) __hip_bfloat16 apL[8192];
  __shared__ float invs[16][8];

  const int tid  = threadIdx.x;
  const int b    = blockIdx.x >> 6;
  const int n0   = (blockIdx.x & 63) << 4;
  const int lane = tid & 63;
  const int wave = tid >> 6;

  if (tid < 128) {
    const int r = tid >> 3, h = tid & 7;
    const size_t row = (size_t)b * SEQ + h * NSEQ + n0 + r;
    invs[r][h] = 1.0f / PSg[row];
  }
  __syncthreads();

  // ---- phase 1: normalize -> hi/lo A-frag pack.
  {
    const int m   = tid & 15;
    const int q   = (tid >> 4) & 3;
    const int kc0 = tid >> 6;
    #pragma unroll
    for (int pss = 0; pss < 4; ++pss) {
      const int kc = kc0 + pss * 4;
      const int h  = kc >> 1;
      const int dh = (q + 4 * (kc & 1)) * 8;
      const size_t idx = (((size_t)b * H_ + h) * NSEQ + n0 + m) * DH + dh;
      const float4 a0 = *(const float4*)(OPg + idx);
      const float4 a1 = *(const float4*)(OPg + idx + 4);
      const float inv = invs[m][h];
      float v[8];
      v[0] = a0.x * inv; v[1] = a0.y * inv;
      v[2] = a0.z * inv; v[3] = a0.w * inv;
      v[4] = a1.x * inv; v[5] = a1.y * inv;
      v[6] = a1.z * inv; v[7] = a1.w * inv;
      bf16x8 hv, lv;
      #pragma unroll
      for (int j = 0; j < 8; ++j) {
        const __bf16 h16 = (__bf16)v[j];
        hv[j] = h16;
        lv[j] = (__bf16)(v[j] - (float)h16);
      }
      const int off = (kc * 64 + (m + 16 * q)) * 8;
      *(bf16x8*)(apH + off) = hv;
      *(bf16x8*)(apL + off) = lv;
    }
  }
  __syncthreads();

  bf16x8 ah[16], al[16];
  #pragma unroll
  for (int kc = 0; kc < 16; ++kc) {
    ah[kc] = *(const bf16x8*)(apH + (kc * 64 + lane) * 8);
    al[kc] = *(const bf16x8*)(apL + (kc * 64 + lane) * 8);
  }

  const int colq = lane & 15;
  const int quad = lane >> 4;

  #pragma unroll
  for (int nt4 = 0; nt4 < 4; ++nt4) {
    const int nt = nt4 * 4 + wave;
    const __hip_bfloat16* wbh = WOBH + ((size_t)nt * 16 * 64 + lane) * 8;
    const __hip_bfloat16* wbl = WOBL + ((size_t)nt * 16 * 64 + lane) * 8;
    floatx4 aHH = (floatx4){0.f, 0.f, 0.f, 0.f};
    floatx4 aHL = (floatx4){0.f, 0.f, 0.f, 0.f};
    floatx4 aLH = (floatx4){0.f, 0.f, 0.f, 0.f};
    #pragma unroll
    for (int kg = 0; kg < 4; ++kg) {
      bf16x8 bh[4], bl[4];
      #pragma unroll
      for (int j = 0; j < 4; ++j) {
        bh[j] = *(const bf16x8*)(wbh + (kg * 4 + j) * 512);
        bl[j] = *(const bf16x8*)(wbl + (kg * 4 + j) * 512);
      }
      #pragma unroll
      for (int j = 0; j < 4; ++j) {
        const int kc = kg * 4 + j;
        aHH = __builtin_amdgcn_mfma_f32_16x16x32_bf16(ah[kc], bh[j], aHH, 0, 0, 0);
        aHL = __builtin_amdgcn_mfma_f32_16x16x32_bf16(ah[kc], bl[j], aHL, 0, 0, 0);
        aLH = __builtin_amdgcn_mfma_f32_16x16x32_bf16(al[kc], bh[j], aLH, 0, 0, 0);
      }
    }
    const int n  = nt * 16 + colq;
    const float bv = bo[n];
    #pragma unroll
    for (int r = 0; r < 4; ++r) {
      const int mm = quad * 4 + r;
      out[((size_t)b * NSEQ + n0 + mm) * QS + n] =
          ((aHH[r] + aHL[r]) + aLH[r]) + bv;
    }
  }
}

extern "C" void kernel_launch(void* const* d_in, const int* in_sizes, int n_in,
                              void* d_out, int out_size, void* d_ws, size_t ws_size,
                              hipStream_t stream) {
  const float* x   = (const float*)d_in[0];
  const float* wq1 = (const float*)d_in[1];
  const float* wq2 = (const float*)d_in[2];
  const float* wk1 = (const float*)d_in[3];
  const float* wk2 = (const float*)d_in[4];
  const float* wv1 = (const float*)d_in[5];
  const float* wv2 = (const float*)d_in[6];
  const float* wo  = (const float*)d_in[7];
  const float* bo  = (const float*)d_in[8];
  float* out = (float*)d_out;

  __hip_bfloat16* Qg  = (__hip_bfloat16*)d_ws;
  __hip_bfloat16* KSg = Qg + (size_t)B_ * SEQ * DH;
  __hip_bfloat16* VSg = KSg + (size_t)B_ * KVSW_BATCH;
  float*          OPg = (float*)(VSg + (size_t)B_ * KVSW_BATCH);   // [B_][SEQ][DH]
  float*          PSg = OPg + (size_t)B_ * SEQ * DH;               // [B_][SEQ]
  __hip_bfloat16* WOBH = (__hip_bfloat16*)(PSg + (size_t)B_ * SEQ);
  __hip_bfloat16* WOBL = WOBH + (size_t)INNER * QS;                // 131072
  __hip_bfloat16* W1BH = WOBL + (size_t)INNER * QS;
  __hip_bfloat16* W1BL = W1BH + 32768;
  __hip_bfloat16* W2BH = W1BL + 32768;
  __hip_bfloat16* W2BL = W2BH + 98304;

  conv_kernel<<<80, 256, 0, stream>>>(wq1, wk1, wv1, wq2, wk2, wv2, wo,
                                      W1BH, W1BL, W2BH, W2BL, WOBH, WOBL);
  qkv_kernel<<<256, 512, 0, stream>>>(x, W1BH, W1BL, W2BH, W2BL, Qg, KSg, VSg);
  attn_kernel<<<512, 512, 0, stream>>>(Qg, KSg, VSg, OPg, PSg);
  out_kernel<<<256, 256, 0, stream>>>(OPg, PSg, WOBH, WOBL, bo, out);
}

// Round 9
// 167.709 us; speedup vs baseline: 1.0837x; 1.0169x over previous
//
#include <hip/hip_runtime.h>
#include <hip/hip_bf16.h>

// CrossAttention: b=4, n=1024, qs=256, heads=8, dim_head=64, bottleneck=40.
// Attention = full 8192x8192 softmax-attention per batch over D=64.
//
// R22:
//  - attn: single-pass kv (no half split) in the R13 BLOCK SHAPE. 512
//    blocks x 256 thr (4 waves = 4 kv quarters, 64 pairs each; loop body
//    and epilogue byte-identical to R13). R21's +6.5us came from the
//    512-thr packaging (VGPR 112, 8-way merge, 19% occ) — not from the
//    split removal (WRITE halved as predicted). Expect VGPR 84 again.
//  - out: merge-free (single OPg/PSg read).
//  - conv/qkv: frozen R17.
//
// Workspace: Q|K_sw|V_sw 12MB | Opart 8MB | psum 128KB | WOB 512KB |
//            W1B 128KB | W2B 384KB ~ 21MB.

#define B_    4
#define H_    8
#define NSEQ  1024
#define SEQ   8192        // H_*NSEQ
#define DH    64
#define QS    256
#define INNER 512
#define QSCALE 0.18033688011112042f   // (1/sqrt(64)) * log2(e)

#define KVSW_BATCH 524288             // elems per batch in K_sw / V_sw

typedef __bf16 bf16x8 __attribute__((ext_vector_type(8)));
typedef float floatx4 __attribute__((ext_vector_type(4)));

// ---------------- kernel 0: weight -> bf16 hi/lo fragment conversion (frozen R17) ----------------
__global__ __launch_bounds__(256) void conv_kernel(
    const float* __restrict__ wq1, const float* __restrict__ wk1,
    const float* __restrict__ wv1,
    const float* __restrict__ wq2, const float* __restrict__ wk2,
    const float* __restrict__ wv2,
    const float* __restrict__ wo,
    __hip_bfloat16* __restrict__ W1BH, __hip_bfloat16* __restrict__ W1BL,
    __hip_bfloat16* __restrict__ W2BH, __hip_bfloat16* __restrict__ W2BL,
    __hip_bfloat16* __restrict__ WOBH, __hip_bfloat16* __restrict__ WOBL)
{
  const int tid = threadIdx.x;
  const int blk = blockIdx.x;

  if (blk < 16) {
    const int t  = blk * 256 + tid;
    const int n  = t & 127;
    const int kq = t >> 7;
    const int kc = kq >> 2, q = kq & 3;
    const float* src; int col;
    if (n < 40)       { src = wq1; col = n; }
    else if (n < 80)  { src = wk1; col = n - 40; }
    else if (n < 120) { src = wv1; col = n - 80; }
    else              { src = nullptr; col = 0; }
    bf16x8 hv, lv;
    #pragma unroll
    for (int j = 0; j < 8; ++j) {
      const int k = kc * 32 + q * 8 + j;
      const float v = src ? src[k * 40 + col] : 0.f;
      const __bf16 h16 = (__bf16)v;
      hv[j] = h16; lv[j] = (__bf16)(v - (float)h16);
    }
    const size_t off = (((size_t)(n >> 4) * 8 + kc) * 64 + (n & 15) + 16 * q) * 8;
    *(bf16x8*)(W1BH + off) = hv;
    *(bf16x8*)(W1BL + off) = lv;
  } else if (blk < 64) {
    const int t  = (blk - 16) * 256 + tid;
    const int n  = t & 511;
    const int r  = t >> 9;                    // [0,24)
    const int p  = r >> 3;
    const int kq = r & 7;
    const int kc = kq >> 2, q = kq & 3;
    const float* w2 = (p == 0) ? wq2 : (p == 1) ? wk2 : wv2;
    bf16x8 hv, lv;
    #pragma unroll
    for (int j = 0; j < 8; ++j) {
      const int k = kc * 32 + q * 8 + j;
      const float v = (k < 40) ? w2[(size_t)k * 512 + n] : 0.f;
      const __bf16 h16 = (__bf16)v;
      hv[j] = h16; lv[j] = (__bf16)(v - (float)h16);
    }
    const size_t off = ((((size_t)p * 32 + (n >> 4)) * 2 + kc) * 64 + (n & 15) + 16 * q) * 8;
    *(bf16x8*)(W2BH + off) = hv;
    *(bf16x8*)(W2BL + off) = lv;
  } else {
    const int cid = blk - 64;                 // [0,16)
    const int t4  = (cid * 256 + tid) * 4;
    const int n   = t4 & 255;
    const int k8  = t4 >> 8;
    float4 rr[8];
    #pragma unroll
    for (int kk = 0; kk < 8; ++kk)
      rr[kk] = *(const float4*)(wo + (size_t)(k8 * 8 + kk) * QS + n);
    const int kc = k8 >> 2, qq = k8 & 3;
    #pragma unroll
    for (int nn = 0; nn < 4; ++nn) {
      const int nc = n + nn;
      const int l  = (nc & 15) + 16 * qq;
      const size_t off = ((size_t)((nc >> 4) * 16 + kc) * 64 + l) * 8;
      bf16x8 hv, lv;
      #pragma unroll
      for (int kk = 0; kk < 8; ++kk) {
        const float v = (nn == 0) ? rr[kk].x : (nn == 1) ? rr[kk].y
                      : (nn == 2) ? rr[kk].z : rr[kk].w;
        const __bf16 h16 = (__bf16)v;
        hv[kk] = h16;
        lv[kk] = (__bf16)(v - (float)h16);
      }
      *(bf16x8*)(WOBH + off) = hv;
      *(bf16x8*)(WOBL + off) = lv;
    }
  }
}

// ---------------- kernel 1: QKV projections, MFMA (frozen R17) ----------------
__global__ __launch_bounds__(512) void qkv_kernel(
    const float* __restrict__ x,
    const __hip_bfloat16* __restrict__ W1BH, const __hip_bfloat16* __restrict__ W1BL,
    const __hip_bfloat16* __restrict__ W2BH, const __hip_bfloat16* __restrict__ W2BL,
    __hip_bfloat16* __restrict__ Qg, __hip_bfloat16* __restrict__ KSg,
    __hip_bfloat16* __restrict__ VSg)
{
  const int tid  = threadIdx.x;
  const int b    = blockIdx.x >> 6;
  const int nblk = blockIdx.x & 63;
  const int n0   = nblk << 4;
  const int wave = tid >> 6;
  const int lane = tid & 63;
  const int m    = lane & 15;     // A-frag row / D col-part
  const int q    = lane >> 4;     // k-subgroup / D row-quad

  __shared__ __align__(16) float xs[16][260];
  __shared__ __align__(16) float tb32[16][140];
  __shared__ __align__(16) __hip_bfloat16 qb[8320];    // [16][520]
  __shared__ __align__(16) __hip_bfloat16 kb[8320];    // [16][520]
  __shared__ __align__(16) __hip_bfloat16 vb[10240];   // [512][20]

  #pragma unroll
  for (int j = 0; j < 2; ++j) {
    const int i  = tid + j * 512;
    const int r  = i >> 6;
    const int c4 = (i & 63) << 2;
    *(float4*)(&xs[r][c4]) =
        *(const float4*)(x + ((size_t)b * NSEQ + n0 + r) * QS + c4);
  }
  __syncthreads();

  bf16x8 xh[8], xl[8];
  #pragma unroll
  for (int kc = 0; kc < 8; ++kc) {
    const float4 f0 = *(const float4*)(&xs[m][kc * 32 + q * 8]);
    const float4 f1 = *(const float4*)(&xs[m][kc * 32 + q * 8 + 4]);
    float v[8] = {f0.x, f0.y, f0.z, f0.w, f1.x, f1.y, f1.z, f1.w};
    #pragma unroll
    for (int j = 0; j < 8; ++j) {
      const __bf16 h16 = (__bf16)v[j];
      xh[kc][j] = h16;
      xl[kc][j] = (__bf16)(v[j] - (float)h16);
    }
  }

  {
    floatx4 hh = (floatx4){0.f, 0.f, 0.f, 0.f};
    floatx4 hl = (floatx4){0.f, 0.f, 0.f, 0.f};
    floatx4 lh = (floatx4){0.f, 0.f, 0.f, 0.f};
    const __hip_bfloat16* w1h = W1BH + ((size_t)wave * 8 * 64 + lane) * 8;
    const __hip_bfloat16* w1l = W1BL + ((size_t)wave * 8 * 64 + lane) * 8;
    #pragma unroll
    for (int kc = 0; kc < 8; ++kc) {
      const bf16x8 bh = *(const bf16x8*)(w1h + kc * 512);
      const bf16x8 bl = *(const bf16x8*)(w1l + kc * 512);
      hh = __builtin_amdgcn_mfma_f32_16x16x32_bf16(xh[kc], bh, hh, 0, 0, 0);
      hl = __builtin_amdgcn_mfma_f32_16x16x32_bf16(xh[kc], bl, hl, 0, 0, 0);
      lh = __builtin_amdgcn_mfma_f32_16x16x32_bf16(xl[kc], bh, lh, 0, 0, 0);
    }
    const int n1 = wave * 16 + m;   // cat col (D col = lane&15)
    #pragma unroll
    for (int r = 0; r < 4; ++r) {
      float d = (hh[r] + hl[r]) + lh[r];
      if (n1 >= 40 && n1 < 80) d = d / (1.f + __expf(-d));   // SiLU on K path
      tb32[q * 4 + r][n1] = d;       // D row = q*4+r
    }
  }
  __syncthreads();

  #pragma unroll
  for (int p = 0; p < 3; ++p) {
    bf16x8 a2h[2], a2l[2];
    {
      const float4 g0 = *(const float4*)(&tb32[m][p * 40 + q * 8]);
      const float4 g1 = *(const float4*)(&tb32[m][p * 40 + q * 8 + 4]);
      float v[8] = {g0.x, g0.y, g0.z, g0.w, g1.x, g1.y, g1.z, g1.w};
      #pragma unroll
      for (int j = 0; j < 8; ++j) {
        const __bf16 h16 = (__bf16)v[j];
        a2h[0][j] = h16;
        a2l[0][j] = (__bf16)(v[j] - (float)h16);
      }
    }
    if (q == 0) {
      const float4 g0 = *(const float4*)(&tb32[m][p * 40 + 32]);
      const float4 g1 = *(const float4*)(&tb32[m][p * 40 + 36]);
      float v[8] = {g0.x, g0.y, g0.z, g0.w, g1.x, g1.y, g1.z, g1.w};
      #pragma unroll
      for (int j = 0; j < 8; ++j) {
        const __bf16 h16 = (__bf16)v[j];
        a2h[1][j] = h16;
        a2l[1][j] = (__bf16)(v[j] - (float)h16);
      }
    } else {
      #pragma unroll
      for (int j = 0; j < 8; ++j) { a2h[1][j] = (__bf16)0.f; a2l[1][j] = (__bf16)0.f; }
    }

    #pragma unroll
    for (int i = 0; i < 4; ++i) {
      const int nt = wave * 4 + i;
      floatx4 sHH = (floatx4){0.f, 0.f, 0.f, 0.f};
      floatx4 sHL = (floatx4){0.f, 0.f, 0.f, 0.f};
      floatx4 sLH = (floatx4){0.f, 0.f, 0.f, 0.f};
      #pragma unroll
      for (int kc = 0; kc < 2; ++kc) {
        const size_t boff = (((size_t)(p * 32 + nt) * 2 + kc) * 64 + lane) * 8;
        const bf16x8 bh = *(const bf16x8*)(W2BH + boff);
        const bf16x8 bl = *(const bf16x8*)(W2BL + boff);
        sHH = __builtin_amdgcn_mfma_f32_16x16x32_bf16(a2h[kc], bh, sHH, 0, 0, 0);
        sHL = __builtin_amdgcn_mfma_f32_16x16x32_bf16(a2h[kc], bl, sHL, 0, 0, 0);
        sLH = __builtin_amdgcn_mfma_f32_16x16x32_bf16(a2l[kc], bh, sLH, 0, 0, 0);
      }
      const int nn = nt * 16 + m;    // output col [0,512)
      #pragma unroll
      for (int r = 0; r < 4; ++r) {
        const int row = q * 4 + r;
        const float d = (sHH[r] + sHL[r]) + sLH[r];
        if (p == 0)      qb[row * 520 + nn] = __float2bfloat16(d * QSCALE);
        else if (p == 1) kb[row * 520 + nn] = __float2bfloat16(d);
        else             vb[nn * 20 + row]  = __float2bfloat16(d);
      }
    }
  }
  __syncthreads();

  #pragma unroll
  for (int j = 0; j < 2; ++j) {
    const int i  = tid + j * 512;
    const int h  = i >> 7;
    const int r  = (i >> 3) & 15;
    const int d8 = i & 7;
    *(float4*)(Qg + ((size_t)b * SEQ + h * NSEQ + n0 + r) * DH + d8 * 8) =
        *(const float4*)(&qb[r * 520 + h * 64 + d8 * 8]);
  }
  #pragma unroll
  for (int j = 0; j < 2; ++j) {
    const int i    = tid + j * 512;
    const int h    = i >> 7;
    const int ks2  = (i >> 6) & 1;
    const int quad = (i >> 4) & 3;
    const int r    = i & 15;
    const int ln   = quad * 16 + r;
    const size_t dst = (size_t)b * KVSW_BATCH
        + ((size_t)((h * 64 + nblk) * 2 + ks2) * 64 + ln) * 8;
    *(float4*)(KSg + dst) = *(const float4*)(&kb[r * 520 + h * 64 + ks2 * 32 + quad * 8]);
  }
  {
    const int st  = nblk & 1;
    const int p32 = nblk >> 1;
    #pragma unroll
    for (int pass = 0; pass < 4; ++pass) {
      const int i   = tid + pass * 512;
      const int h   = i >> 8;
      const int dnt = (i >> 6) & 3;
      const int dm  = (i >> 2) & 15;
      const int rg  = i & 3;
      const int ln  = rg * 16 + dm;
      const size_t dst = (size_t)b * KVSW_BATCH
          + ((size_t)((h * 32 + p32) * 4 + dnt) * 64 + ln) * 8 + st * 4;
      *(uint2*)(VSg + dst) = *(const uint2*)(&vb[(h * 64 + dnt * 16 + dm) * 20 + rg * 4]);
    }
  }
}

// ---------------- kernel 2: attention — single-pass kv, R13 block shape ----------------
// 512 blocks (xcd = blk&7: b = xcd>>1; qtile = (xcd&1)*64 + blk>>3),
// 256 thr: wave = kv QUARTER (2048 rows = 64 pairs). Loop body and
// epilogue identical to R13 (4-way Osh merge); Opart/PSg written once.
struct PairBuf {
  bf16x8 k[2][2];   // [strip][k-span]
  bf16x8 v[4];      // [d-tile]
};

__global__ __launch_bounds__(256, 3) void attn_kernel(
    const __hip_bfloat16* __restrict__ Qg,
    const __hip_bfloat16* __restrict__ KSg,
    const __hip_bfloat16* __restrict__ VSg,
    float* __restrict__ OPg,       // [B_][SEQ][DH]
    float* __restrict__ PSg)       // [B_][SEQ]
{
  __shared__ float Osh[4][16][68];
  __shared__ float psums[4][64];

  const int tid  = threadIdx.x;
  const int wave = tid >> 6;       // [0,4) — kv quarter
  const int lane = tid & 63;
  const int lrow = lane & 15;
  const int quad = lane >> 4;

  const int xcd   = blockIdx.x & 7;
  const int idx   = blockIdx.x >> 3;       // [0,64)
  const int b     = xcd >> 1;
  const int qtile = (xcd & 1) * 64 + idx;  // [0,128)
  const int qbase = qtile * 64;

  const __hip_bfloat16* Qb  = Qg + ((size_t)b * SEQ + qbase) * DH;
  const __hip_bfloat16* kp0 = KSg + (size_t)b * KVSW_BATCH
                              + (size_t)wave * 131072 + lane * 8;
  const __hip_bfloat16* vp0 = VSg + (size_t)b * KVSW_BATCH
                              + (size_t)wave * 131072 + lane * 8;

  bf16x8 qf[4][2];
  #pragma unroll
  for (int mt = 0; mt < 4; ++mt)
    #pragma unroll
    for (int s = 0; s < 2; ++s)
      qf[mt][s] = *(const bf16x8*)(Qb + (mt * 16 + lrow) * DH + s * 32 + quad * 8);

  floatx4 oacc[4][4];   // [mt][dnt] — 64 acc regs (unified budget)
  #pragma unroll
  for (int mt = 0; mt < 4; ++mt)
    #pragma unroll
    for (int dnt = 0; dnt < 4; ++dnt)
      oacc[mt][dnt] = (floatx4){0.f, 0.f, 0.f, 0.f};
  float psum[4] = {0.f, 0.f, 0.f, 0.f};

  #pragma unroll 2
  for (int pair = 0; pair < 64; ++pair) {
    PairBuf pb;
    const __hip_bfloat16* kp = kp0 + pair * 2048;
    pb.k[0][0] = *(const bf16x8*)(kp);
    pb.k[0][1] = *(const bf16x8*)(kp + 512);
    pb.k[1][0] = *(const bf16x8*)(kp + 1024);
    pb.k[1][1] = *(const bf16x8*)(kp + 1536);
    const __hip_bfloat16* vp = vp0 + pair * 2048;
    #pragma unroll
    for (int dnt = 0; dnt < 4; ++dnt)
      pb.v[dnt] = *(const bf16x8*)(vp + dnt * 512);

    #pragma unroll
    for (int mt = 0; mt < 4; ++mt) {
      floatx4 s0 = (floatx4){0.f, 0.f, 0.f, 0.f};
      floatx4 s1 = (floatx4){0.f, 0.f, 0.f, 0.f};
      s0 = __builtin_amdgcn_mfma_f32_16x16x32_bf16(pb.k[0][0], qf[mt][0], s0, 0, 0, 0);
      s0 = __builtin_amdgcn_mfma_f32_16x16x32_bf16(pb.k[0][1], qf[mt][1], s0, 0, 0, 0);
      s1 = __builtin_amdgcn_mfma_f32_16x16x32_bf16(pb.k[1][0], qf[mt][0], s1, 0, 0, 0);
      s1 = __builtin_amdgcn_mfma_f32_16x16x32_bf16(pb.k[1][1], qf[mt][1], s1, 0, 0, 0);
      float p[8];
      #pragma unroll
      for (int r = 0; r < 4; ++r) {
        p[r]     = __builtin_amdgcn_exp2f(s0[r]);
        p[4 + r] = __builtin_amdgcn_exp2f(s1[r]);
      }
      psum[mt] += ((p[0] + p[1]) + (p[2] + p[3])) + ((p[4] + p[5]) + (p[6] + p[7]));
      bf16x8 pa;
      #pragma unroll
      for (int j = 0; j < 8; ++j) pa[j] = (__bf16)p[j];
      #pragma unroll
      for (int dnt = 0; dnt < 4; ++dnt)
        oacc[mt][dnt] = __builtin_amdgcn_mfma_f32_16x16x32_bf16(pa, pb.v[dnt], oacc[mt][dnt], 0, 0, 0);
    }
  }

  #pragma unroll
  for (int mt = 0; mt < 4; ++mt) {
    float s = psum[mt];
    s += __shfl_xor(s, 16, 64);
    s += __shfl_xor(s, 32, 64);
    psum[mt] = s;
  }
  if (quad == 0) {
    #pragma unroll
    for (int mt = 0; mt < 4; ++mt)
      psums[wave][mt * 16 + lrow] = psum[mt];
  }

  const size_t opbase = (size_t)b * SEQ + qbase;

  #pragma unroll
  for (int mt = 0; mt < 4; ++mt) {
    #pragma unroll
    for (int dnt = 0; dnt < 4; ++dnt)
      #pragma unroll
      for (int r = 0; r < 4; ++r)
        Osh[wave][quad * 4 + r][dnt * 16 + lrow] = oacc[mt][dnt][r];
    __syncthreads();

    {
      const int q16 = tid >> 4;
      const int d0  = (tid & 15) * 4;
      float4 a0 = *(const float4*)(&Osh[0][q16][d0]);
      float4 a1 = *(const float4*)(&Osh[1][q16][d0]);
      float4 a2 = *(const float4*)(&Osh[2][q16][d0]);
      float4 a3 = *(const float4*)(&Osh[3][q16][d0]);
      float4 res;
      res.x = (a0.x + a1.x) + (a2.x + a3.x);
      res.y = (a0.y + a1.y) + (a2.y + a3.y);
      res.z = (a0.z + a1.z) + (a2.z + a3.z);
      res.w = (a0.w + a1.w) + (a2.w + a3.w);
      *(float4*)(OPg + (opbase + mt * 16 + q16) * DH + d0) = res;
    }
    if (mt == 0 && tid < 64) {
      const float tot = (psums[0][tid] + psums[1][tid]) + (psums[2][tid] + psums[3][tid]);
      PSg[opbase + tid] = tot;
    }
    __syncthreads();
  }
}

// ---------------- kernel 3: out = (Opart/denom) @ wo + bo — MFMA (merge-free) ----------------
__global__ __launch_bounds__(256, 1) void out_kernel(
    const float* __restrict__ OPg, const float* __restrict__ PSg,
    const __hip_bfloat16* __restrict__ WOBH, const __hip_bfloat16* __restrict__ WOBL,
    const float* __restrict__ bo, float* __restrict__ out)
{
  __shared__ __align__(16) __hip_bfloat16 apH[8192];   // [kc][lane][8]
  __shared__ __align__(16) __hip_bfloat16 apL[8192];
  __shared__ float invs[16][8];

  const int tid  = threadIdx.x;
  const int b    = blockIdx.x >> 6;
  const int n0   = (blockIdx.x & 63) << 4;
  const int lane = tid & 63;
  const int wave = tid >> 6;

  if (tid < 128) {
    const int r = tid >> 3, h = tid & 7;
    const size_t row = (size_t)b * SEQ + h * NSEQ + n0 + r;
    invs[r][h] = 1.0f / PSg[row];
  }
  __syncthreads();

  // ---- phase 1: normalize -> hi/lo A-frag pack.
  {
    const int m   = tid & 15;
    const int q   = (tid >> 4) & 3;
    const int kc0 = tid >> 6;
    #pragma unroll
    for (int pss = 0; pss < 4; ++pss) {
      const int kc = kc0 + pss * 4;
      const int h  = kc >> 1;
      const int dh = (q + 4 * (kc & 1)) * 8;
      const size_t idx = (((size_t)b * H_ + h) * NSEQ + n0 + m) * DH + dh;
      const float4 a0 = *(const float4*)(OPg + idx);
      const float4 a1 = *(const float4*)(OPg + idx + 4);
      const float inv = invs[m][h];
      float v[8];
      v[0] = a0.x * inv; v[1] = a0.y * inv;
      v[2] = a0.z * inv; v[3] = a0.w * inv;
      v[4] = a1.x * inv; v[5] = a1.y * inv;
      v[6] = a1.z * inv; v[7] = a1.w * inv;
      bf16x8 hv, lv;
      #pragma unroll
      for (int j = 0; j < 8; ++j) {
        const __bf16 h16 = (__bf16)v[j];
        hv[j] = h16;
        lv[j] = (__bf16)(v[j] - (float)h16);
      }
      const int off = (kc * 64 + (m + 16 * q)) * 8;
      *(bf16x8*)(apH + off) = hv;
      *(bf16x8*)(apL + off) = lv;
    }
  }
  __syncthreads();

  bf16x8 ah[16], al[16];
  #pragma unroll
  for (int kc = 0; kc < 16; ++kc) {
    ah[kc] = *(const bf16x8*)(apH + (kc * 64 + lane) * 8);
    al[kc] = *(const bf16x8*)(apL + (kc * 64 + lane) * 8);
  }

  const int colq = lane & 15;
  const int quad = lane >> 4;

  #pragma unroll
  for (int nt4 = 0; nt4 < 4; ++nt4) {
    const int nt = nt4 * 4 + wave;
    const __hip_bfloat16* wbh = WOBH + ((size_t)nt * 16 * 64 + lane) * 8;
    const __hip_bfloat16* wbl = WOBL + ((size_t)nt * 16 * 64 + lane) * 8;
    floatx4 aHH = (floatx4){0.f, 0.f, 0.f, 0.f};
    floatx4 aHL = (floatx4){0.f, 0.f, 0.f, 0.f};
    floatx4 aLH = (floatx4){0.f, 0.f, 0.f, 0.f};
    #pragma unroll
    for (int kg = 0; kg < 4; ++kg) {
      bf16x8 bh[4], bl[4];
      #pragma unroll
      for (int j = 0; j < 4; ++j) {
        bh[j] = *(const bf16x8*)(wbh + (kg * 4 + j) * 512);
        bl[j] = *(const bf16x8*)(wbl + (kg * 4 + j) * 512);
      }
      #pragma unroll
      for (int j = 0; j < 4; ++j) {
        const int kc = kg * 4 + j;
        aHH = __builtin_amdgcn_mfma_f32_16x16x32_bf16(ah[kc], bh[j], aHH, 0, 0, 0);
        aHL = __builtin_amdgcn_mfma_f32_16x16x32_bf16(ah[kc], bl[j], aHL, 0, 0, 0);
        aLH = __builtin_amdgcn_mfma_f32_16x16x32_bf16(al[kc], bh[j], aLH, 0, 0, 0);
      }
    }
    const int n  = nt * 16 + colq;
    const float bv = bo[n];
    #pragma unroll
    for (int r = 0; r < 4; ++r) {
      const int mm = quad * 4 + r;
      out[((size_t)b * NSEQ + n0 + mm) * QS + n] =
          ((aHH[r] + aHL[r]) + aLH[r]) + bv;
    }
  }
}

extern "C" void kernel_launch(void* const* d_in, const int* in_sizes, int n_in,
                              void* d_out, int out_size, void* d_ws, size_t ws_size,
                              hipStream_t stream) {
  const float* x   = (const float*)d_in[0];
  const float* wq1 = (const float*)d_in[1];
  const float* wq2 = (const float*)d_in[2];
  const float* wk1 = (const float*)d_in[3];
  const float* wk2 = (const float*)d_in[4];
  const float* wv1 = (const float*)d_in[5];
  const float* wv2 = (const float*)d_in[6];
  const float* wo  = (const float*)d_in[7];
  const float* bo  = (const float*)d_in[8];
  float* out = (float*)d_out;

  __hip_bfloat16* Qg  = (__hip_bfloat16*)d_ws;
  __hip_bfloat16* KSg = Qg + (size_t)B_ * SEQ * DH;
  __hip_bfloat16* VSg = KSg + (size_t)B_ * KVSW_BATCH;
  float*          OPg = (float*)(VSg + (size_t)B_ * KVSW_BATCH);   // [B_][SEQ][DH]
  float*          PSg = OPg + (size_t)B_ * SEQ * DH;               // [B_][SEQ]
  __hip_bfloat16* WOBH = (__hip_bfloat16*)(PSg + (size_t)B_ * SEQ);
  __hip_bfloat16* WOBL = WOBH + (size_t)INNER * QS;                // 131072
  __hip_bfloat16* W1BH = WOBL + (size_t)INNER * QS;
  __hip_bfloat16* W1BL = W1BH + 32768;
  __hip_bfloat16* W2BH = W1BL + 32768;
  __hip_bfloat16* W2BL = W2BH + 98304;

  conv_kernel<<<80, 256, 0, stream>>>(wq1, wk1, wv1, wq2, wk2, wv2, wo,
                                      W1BH, W1BL, W2BH, W2BL, WOBH, WOBL);
  qkv_kernel<<<256, 512, 0, stream>>>(x, W1BH, W1BL, W2BH, W2BL, Qg, KSg, VSg);
  attn_kernel<<<512, 256, 0, stream>>>(Qg, KSg, VSg, OPg, PSg);
  out_kernel<<<256, 256, 0, stream>>>(OPg, PSg, WOBH, WOBL, bo, out);
}

// Round 10
// 166.771 us; speedup vs baseline: 1.0898x; 1.0056x over previous
//
#include <hip/hip_runtime.h>
#include <hip/hip_bf16.h>

// CrossAttention: b=4, n=1024, qs=256, heads=8, dim_head=64, bottleneck=40.
// Attention = full 8192x8192 softmax-attention per batch over D=64.
//
// R23: EXACT restoration of R17 — the best verified configuration
// (165.2us). R22's single-pass attn (512 blocks = 2/CU, no queue depth)
// ran 76.4us vs the half-split 1024-block shape's 73.3us; occupancy
// 17.9% vs 24%. Non-attn time identical (91.0 vs 91.3us). Campaign
// ledger: 6 attn variants beyond R13-shape all neutral-or-worse.
//  - conv: weight->bf16 hi/lo fragments (grid 80).
//  - qkv: fused MFMA GEMM (grid 256 x 512 thr).
//  - attn: R13 frozen — 1024 blocks x 256 thr, kv-half split, 2 waves/SIMD.
//  - out: merge(Opart halves)/denom @ wo via MFMA hi/lo.
//
// Workspace: Q|K_sw|V_sw 12MB | Opart 16MB | psum 256KB | WOB 512KB |
//            W1B 128KB | W2B 384KB ~ 29.3MB.

#define B_    4
#define H_    8
#define NSEQ  1024
#define SEQ   8192        // H_*NSEQ
#define DH    64
#define QS    256
#define INNER 512
#define QSCALE 0.18033688011112042f   // (1/sqrt(64)) * log2(e)

#define KVSW_BATCH 524288             // elems per batch in K_sw / V_sw
#define OPHALF (2097152)              // B_*SEQ*DH

typedef __bf16 bf16x8 __attribute__((ext_vector_type(8)));
typedef float floatx4 __attribute__((ext_vector_type(4)));

// ---------------- kernel 0: weight -> bf16 hi/lo fragment conversion ----------------
// grid 80, 256 thr. blocks [0,16): w1cat (256x128, cols 120-127 zero);
// [16,64): w2 per proj (K 40->64 zero-pad, N=512); [64,80): wo.
__global__ __launch_bounds__(256) void conv_kernel(
    const float* __restrict__ wq1, const float* __restrict__ wk1,
    const float* __restrict__ wv1,
    const float* __restrict__ wq2, const float* __restrict__ wk2,
    const float* __restrict__ wv2,
    const float* __restrict__ wo,
    __hip_bfloat16* __restrict__ W1BH, __hip_bfloat16* __restrict__ W1BL,
    __hip_bfloat16* __restrict__ W2BH, __hip_bfloat16* __restrict__ W2BL,
    __hip_bfloat16* __restrict__ WOBH, __hip_bfloat16* __restrict__ WOBL)
{
  const int tid = threadIdx.x;
  const int blk = blockIdx.x;

  if (blk < 16) {
    // ---- W1B: task t -> n = t&127, kq = t>>7 (kc = kq>>2, q = kq&3)
    const int t  = blk * 256 + tid;
    const int n  = t & 127;
    const int kq = t >> 7;
    const int kc = kq >> 2, q = kq & 3;
    const float* src; int col;
    if (n < 40)       { src = wq1; col = n; }
    else if (n < 80)  { src = wk1; col = n - 40; }
    else if (n < 120) { src = wv1; col = n - 80; }
    else              { src = nullptr; col = 0; }
    bf16x8 hv, lv;
    #pragma unroll
    for (int j = 0; j < 8; ++j) {
      const int k = kc * 32 + q * 8 + j;
      const float v = src ? src[k * 40 + col] : 0.f;
      const __bf16 h16 = (__bf16)v;
      hv[j] = h16; lv[j] = (__bf16)(v - (float)h16);
    }
    const size_t off = (((size_t)(n >> 4) * 8 + kc) * 64 + (n & 15) + 16 * q) * 8;
    *(bf16x8*)(W1BH + off) = hv;
    *(bf16x8*)(W1BL + off) = lv;
  } else if (blk < 64) {
    // ---- W2B: task t -> n = t&511, r = t>>9 (p = r>>3, kc = (r>>2)&1, q = r&3)
    const int t  = (blk - 16) * 256 + tid;
    const int n  = t & 511;
    const int r  = t >> 9;                    // [0,24)
    const int p  = r >> 3;
    const int kq = r & 7;
    const int kc = kq >> 2, q = kq & 3;
    const float* w2 = (p == 0) ? wq2 : (p == 1) ? wk2 : wv2;
    bf16x8 hv, lv;
    #pragma unroll
    for (int j = 0; j < 8; ++j) {
      const int k = kc * 32 + q * 8 + j;
      const float v = (k < 40) ? w2[(size_t)k * 512 + n] : 0.f;
      const __bf16 h16 = (__bf16)v;
      hv[j] = h16; lv[j] = (__bf16)(v - (float)h16);
    }
    const size_t off = ((((size_t)p * 32 + (n >> 4)) * 2 + kc) * 64 + (n & 15) + 16 * q) * 8;
    *(bf16x8*)(W2BH + off) = hv;
    *(bf16x8*)(W2BL + off) = lv;
  } else {
    // ---- WOB: harness-verified fragment conversion (R16 math).
    const int cid = blk - 64;                 // [0,16)
    const int t4  = (cid * 256 + tid) * 4;
    const int n   = t4 & 255;
    const int k8  = t4 >> 8;
    float4 rr[8];
    #pragma unroll
    for (int kk = 0; kk < 8; ++kk)
      rr[kk] = *(const float4*)(wo + (size_t)(k8 * 8 + kk) * QS + n);
    const int kc = k8 >> 2, qq = k8 & 3;
    #pragma unroll
    for (int nn = 0; nn < 4; ++nn) {
      const int nc = n + nn;
      const int l  = (nc & 15) + 16 * qq;
      const size_t off = ((size_t)((nc >> 4) * 16 + kc) * 64 + l) * 8;
      bf16x8 hv, lv;
      #pragma unroll
      for (int kk = 0; kk < 8; ++kk) {
        const float v = (nn == 0) ? rr[kk].x : (nn == 1) ? rr[kk].y
                      : (nn == 2) ? rr[kk].z : rr[kk].w;
        const __bf16 h16 = (__bf16)v;
        hv[kk] = h16;
        lv[kk] = (__bf16)(v - (float)h16);
      }
      *(bf16x8*)(WOBH + off) = hv;
      *(bf16x8*)(WOBL + off) = lv;
    }
  }
}

// ---------------- kernel 1: QKV projections, MFMA (frozen R17) ----------------
// grid 256 (b*64 + nblk), 512 thr (8 waves), 16 x-rows per block, all 3 proj.
__global__ __launch_bounds__(512) void qkv_kernel(
    const float* __restrict__ x,
    const __hip_bfloat16* __restrict__ W1BH, const __hip_bfloat16* __restrict__ W1BL,
    const __hip_bfloat16* __restrict__ W2BH, const __hip_bfloat16* __restrict__ W2BL,
    __hip_bfloat16* __restrict__ Qg, __hip_bfloat16* __restrict__ KSg,
    __hip_bfloat16* __restrict__ VSg)
{
  const int tid  = threadIdx.x;
  const int b    = blockIdx.x >> 6;
  const int nblk = blockIdx.x & 63;
  const int n0   = nblk << 4;
  const int wave = tid >> 6;
  const int lane = tid & 63;
  const int m    = lane & 15;     // A-frag row / D col-part
  const int q    = lane >> 4;     // k-subgroup / D row-quad

  __shared__ __align__(16) float xs[16][260];
  __shared__ __align__(16) float tb32[16][140];
  __shared__ __align__(16) __hip_bfloat16 qb[8320];    // [16][520]
  __shared__ __align__(16) __hip_bfloat16 kb[8320];    // [16][520]
  __shared__ __align__(16) __hip_bfloat16 vb[10240];   // [512][20]

  #pragma unroll
  for (int j = 0; j < 2; ++j) {
    const int i  = tid + j * 512;
    const int r  = i >> 6;
    const int c4 = (i & 63) << 2;
    *(float4*)(&xs[r][c4]) =
        *(const float4*)(x + ((size_t)b * NSEQ + n0 + r) * QS + c4);
  }
  __syncthreads();

  // ---- build x A-frags (hi/lo), all 8 K-chunks: row m, k = kc*32+q*8+j
  bf16x8 xh[8], xl[8];
  #pragma unroll
  for (int kc = 0; kc < 8; ++kc) {
    const float4 f0 = *(const float4*)(&xs[m][kc * 32 + q * 8]);
    const float4 f1 = *(const float4*)(&xs[m][kc * 32 + q * 8 + 4]);
    float v[8] = {f0.x, f0.y, f0.z, f0.w, f1.x, f1.y, f1.z, f1.w};
    #pragma unroll
    for (int j = 0; j < 8; ++j) {
      const __bf16 h16 = (__bf16)v[j];
      xh[kc][j] = h16;
      xl[kc][j] = (__bf16)(v[j] - (float)h16);
    }
  }

  // ---- stage 1: wave w owns cat n-tile w. 24 MFMA (3-chain hi/lo).
  {
    floatx4 hh = (floatx4){0.f, 0.f, 0.f, 0.f};
    floatx4 hl = (floatx4){0.f, 0.f, 0.f, 0.f};
    floatx4 lh = (floatx4){0.f, 0.f, 0.f, 0.f};
    const __hip_bfloat16* w1h = W1BH + ((size_t)wave * 8 * 64 + lane) * 8;
    const __hip_bfloat16* w1l = W1BL + ((size_t)wave * 8 * 64 + lane) * 8;
    #pragma unroll
    for (int kc = 0; kc < 8; ++kc) {
      const bf16x8 bh = *(const bf16x8*)(w1h + kc * 512);
      const bf16x8 bl = *(const bf16x8*)(w1l + kc * 512);
      hh = __builtin_amdgcn_mfma_f32_16x16x32_bf16(xh[kc], bh, hh, 0, 0, 0);
      hl = __builtin_amdgcn_mfma_f32_16x16x32_bf16(xh[kc], bl, hl, 0, 0, 0);
      lh = __builtin_amdgcn_mfma_f32_16x16x32_bf16(xl[kc], bh, lh, 0, 0, 0);
    }
    const int n1 = wave * 16 + m;   // cat col (D col = lane&15)
    #pragma unroll
    for (int r = 0; r < 4; ++r) {
      float d = (hh[r] + hl[r]) + lh[r];
      if (n1 >= 40 && n1 < 80) d = d / (1.f + __expf(-d));   // SiLU on K path
      tb32[q * 4 + r][n1] = d;       // D row = q*4+r
    }
  }
  __syncthreads();

  // ---- stage 2: per proj p (compile-time), wave covers n-tiles wave*4+i.
  #pragma unroll
  for (int p = 0; p < 3; ++p) {
    bf16x8 a2h[2], a2l[2];
    {
      const float4 g0 = *(const float4*)(&tb32[m][p * 40 + q * 8]);
      const float4 g1 = *(const float4*)(&tb32[m][p * 40 + q * 8 + 4]);
      float v[8] = {g0.x, g0.y, g0.z, g0.w, g1.x, g1.y, g1.z, g1.w};
      #pragma unroll
      for (int j = 0; j < 8; ++j) {
        const __bf16 h16 = (__bf16)v[j];
        a2h[0][j] = h16;
        a2l[0][j] = (__bf16)(v[j] - (float)h16);
      }
    }
    if (q == 0) {
      const float4 g0 = *(const float4*)(&tb32[m][p * 40 + 32]);
      const float4 g1 = *(const float4*)(&tb32[m][p * 40 + 36]);
      float v[8] = {g0.x, g0.y, g0.z, g0.w, g1.x, g1.y, g1.z, g1.w};
      #pragma unroll
      for (int j = 0; j < 8; ++j) {
        const __bf16 h16 = (__bf16)v[j];
        a2h[1][j] = h16;
        a2l[1][j] = (__bf16)(v[j] - (float)h16);
      }
    } else {
      #pragma unroll
      for (int j = 0; j < 8; ++j) { a2h[1][j] = (__bf16)0.f; a2l[1][j] = (__bf16)0.f; }
    }

    #pragma unroll
    for (int i = 0; i < 4; ++i) {
      const int nt = wave * 4 + i;
      floatx4 sHH = (floatx4){0.f, 0.f, 0.f, 0.f};
      floatx4 sHL = (floatx4){0.f, 0.f, 0.f, 0.f};
      floatx4 sLH = (floatx4){0.f, 0.f, 0.f, 0.f};
      #pragma unroll
      for (int kc = 0; kc < 2; ++kc) {
        const size_t boff = (((size_t)(p * 32 + nt) * 2 + kc) * 64 + lane) * 8;
        const bf16x8 bh = *(const bf16x8*)(W2BH + boff);
        const bf16x8 bl = *(const bf16x8*)(W2BL + boff);
        sHH = __builtin_amdgcn_mfma_f32_16x16x32_bf16(a2h[kc], bh, sHH, 0, 0, 0);
        sHL = __builtin_amdgcn_mfma_f32_16x16x32_bf16(a2h[kc], bl, sHL, 0, 0, 0);
        sLH = __builtin_amdgcn_mfma_f32_16x16x32_bf16(a2l[kc], bh, sLH, 0, 0, 0);
      }
      const int nn = nt * 16 + m;    // output col [0,512)
      #pragma unroll
      for (int r = 0; r < 4; ++r) {
        const int row = q * 4 + r;
        const float d = (sHH[r] + sHL[r]) + sLH[r];
        if (p == 0)      qb[row * 520 + nn] = __float2bfloat16(d * QSCALE);
        else if (p == 1) kb[row * 520 + nn] = __float2bfloat16(d);
        else             vb[nn * 20 + row]  = __float2bfloat16(d);
      }
    }
  }
  __syncthreads();

  // ---- Q write: 1024 float4 tasks, 2 per thread ----
  #pragma unroll
  for (int j = 0; j < 2; ++j) {
    const int i  = tid + j * 512;
    const int h  = i >> 7;
    const int r  = (i >> 3) & 15;
    const int d8 = i & 7;
    *(float4*)(Qg + ((size_t)b * SEQ + h * NSEQ + n0 + r) * DH + d8 * 8) =
        *(const float4*)(&qb[r * 520 + h * 64 + d8 * 8]);
  }
  // ---- K_sw write: 1024 float4 tasks, 2 per thread ----
  #pragma unroll
  for (int j = 0; j < 2; ++j) {
    const int i    = tid + j * 512;
    const int h    = i >> 7;
    const int ks2  = (i >> 6) & 1;
    const int quad = (i >> 4) & 3;
    const int r    = i & 15;
    const int ln   = quad * 16 + r;
    const size_t dst = (size_t)b * KVSW_BATCH
        + ((size_t)((h * 64 + nblk) * 2 + ks2) * 64 + ln) * 8;
    *(float4*)(KSg + dst) = *(const float4*)(&kb[r * 520 + h * 64 + ks2 * 32 + quad * 8]);
  }
  // ---- V_sw write: 2048 uint2 tasks, 4 per thread ----
  {
    const int st  = nblk & 1;
    const int p32 = nblk >> 1;
    #pragma unroll
    for (int pass = 0; pass < 4; ++pass) {
      const int i   = tid + pass * 512;
      const int h   = i >> 8;
      const int dnt = (i >> 6) & 3;
      const int dm  = (i >> 2) & 15;
      const int rg  = i & 3;
      const int ln  = rg * 16 + dm;
      const size_t dst = (size_t)b * KVSW_BATCH
          + ((size_t)((h * 32 + p32) * 4 + dnt) * 64 + ln) * 8 + st * 4;
      *(uint2*)(VSg + dst) = *(const uint2*)(&vb[(h * 64 + dnt * 16 + dm) * 20 + rg * 4]);
    }
  }
}

// ---------------- kernel 2: attention, kv-split partial blocks (frozen R13) ----------------
struct PairBuf {
  bf16x8 k[2][2];   // [strip][k-span]
  bf16x8 v[4];      // [d-tile]
};

__global__ __launch_bounds__(256, 3) void attn_kernel(
    const __hip_bfloat16* __restrict__ Qg,
    const __hip_bfloat16* __restrict__ KSg,
    const __hip_bfloat16* __restrict__ VSg,
    float* __restrict__ OPg,       // [2][B_][SEQ][DH]
    float* __restrict__ PSg)       // [2][B_][SEQ]
{
  __shared__ float Osh[4][16][68];
  __shared__ float psums[4][64];

  const int tid  = threadIdx.x;
  const int wave = tid >> 6;
  const int lane = tid & 63;
  const int lrow = lane & 15;
  const int quad = lane >> 4;

  const int xcd   = blockIdx.x & 7;
  const int idx   = blockIdx.x >> 3;       // [0,128)
  const int b     = xcd >> 1;
  const int half  = idx & 1;
  const int qtile = (xcd & 1) * 64 + (idx >> 1);
  const int qbase = qtile * 64;

  const __hip_bfloat16* Qb  = Qg + ((size_t)b * SEQ + qbase) * DH;
  const __hip_bfloat16* kp0 = KSg + (size_t)b * KVSW_BATCH + half * 262144
                              + (size_t)wave * 65536 + lane * 8;
  const __hip_bfloat16* vp0 = VSg + (size_t)b * KVSW_BATCH + half * 262144
                              + (size_t)wave * 65536 + lane * 8;

  bf16x8 qf[4][2];
  #pragma unroll
  for (int mt = 0; mt < 4; ++mt)
    #pragma unroll
    for (int s = 0; s < 2; ++s)
      qf[mt][s] = *(const bf16x8*)(Qb + (mt * 16 + lrow) * DH + s * 32 + quad * 8);

  floatx4 oacc[4][4];   // [mt][dnt] — 64 acc regs (unified budget)
  #pragma unroll
  for (int mt = 0; mt < 4; ++mt)
    #pragma unroll
    for (int dnt = 0; dnt < 4; ++dnt)
      oacc[mt][dnt] = (floatx4){0.f, 0.f, 0.f, 0.f};
  float psum[4] = {0.f, 0.f, 0.f, 0.f};

  #pragma unroll 2
  for (int pair = 0; pair < 32; ++pair) {
    PairBuf pb;
    const __hip_bfloat16* kp = kp0 + pair * 2048;
    pb.k[0][0] = *(const bf16x8*)(kp);
    pb.k[0][1] = *(const bf16x8*)(kp + 512);
    pb.k[1][0] = *(const bf16x8*)(kp + 1024);
    pb.k[1][1] = *(const bf16x8*)(kp + 1536);
    const __hip_bfloat16* vp = vp0 + pair * 2048;
    #pragma unroll
    for (int dnt = 0; dnt < 4; ++dnt)
      pb.v[dnt] = *(const bf16x8*)(vp + dnt * 512);

    #pragma unroll
    for (int mt = 0; mt < 4; ++mt) {
      floatx4 s0 = (floatx4){0.f, 0.f, 0.f, 0.f};
      floatx4 s1 = (floatx4){0.f, 0.f, 0.f, 0.f};
      s0 = __builtin_amdgcn_mfma_f32_16x16x32_bf16(pb.k[0][0], qf[mt][0], s0, 0, 0, 0);
      s0 = __builtin_amdgcn_mfma_f32_16x16x32_bf16(pb.k[0][1], qf[mt][1], s0, 0, 0, 0);
      s1 = __builtin_amdgcn_mfma_f32_16x16x32_bf16(pb.k[1][0], qf[mt][0], s1, 0, 0, 0);
      s1 = __builtin_amdgcn_mfma_f32_16x16x32_bf16(pb.k[1][1], qf[mt][1], s1, 0, 0, 0);
      float p[8];
      #pragma unroll
      for (int r = 0; r < 4; ++r) {
        p[r]     = __builtin_amdgcn_exp2f(s0[r]);
        p[4 + r] = __builtin_amdgcn_exp2f(s1[r]);
      }
      psum[mt] += ((p[0] + p[1]) + (p[2] + p[3])) + ((p[4] + p[5]) + (p[6] + p[7]));
      bf16x8 pa;
      #pragma unroll
      for (int j = 0; j < 8; ++j) pa[j] = (__bf16)p[j];
      #pragma unroll
      for (int dnt = 0; dnt < 4; ++dnt)
        oacc[mt][dnt] = __builtin_amdgcn_mfma_f32_16x16x32_bf16(pa, pb.v[dnt], oacc[mt][dnt], 0, 0, 0);
    }
  }

  #pragma unroll
  for (int mt = 0; mt < 4; ++mt) {
    float s = psum[mt];
    s += __shfl_xor(s, 16, 64);
    s += __shfl_xor(s, 32, 64);
    psum[mt] = s;
  }
  if (quad == 0) {
    #pragma unroll
    for (int mt = 0; mt < 4; ++mt)
      psums[wave][mt * 16 + lrow] = psum[mt];
  }

  const size_t opbase = ((size_t)half * B_ + b) * SEQ + qbase;

  #pragma unroll
  for (int mt = 0; mt < 4; ++mt) {
    #pragma unroll
    for (int dnt = 0; dnt < 4; ++dnt)
      #pragma unroll
      for (int r = 0; r < 4; ++r)
        Osh[wave][quad * 4 + r][dnt * 16 + lrow] = oacc[mt][dnt][r];
    __syncthreads();

    {
      const int q16 = tid >> 4;
      const int d0  = (tid & 15) * 4;
      float4 a0 = *(const float4*)(&Osh[0][q16][d0]);
      float4 a1 = *(const float4*)(&Osh[1][q16][d0]);
      float4 a2 = *(const float4*)(&Osh[2][q16][d0]);
      float4 a3 = *(const float4*)(&Osh[3][q16][d0]);
      float4 res;
      res.x = (a0.x + a1.x) + (a2.x + a3.x);
      res.y = (a0.y + a1.y) + (a2.y + a3.y);
      res.z = (a0.z + a1.z) + (a2.z + a3.z);
      res.w = (a0.w + a1.w) + (a2.w + a3.w);
      *(float4*)(OPg + (opbase + mt * 16 + q16) * DH + d0) = res;
    }
    if (mt == 0 && tid < 64) {
      const float tot = (psums[0][tid] + psums[1][tid]) + (psums[2][tid] + psums[3][tid]);
      PSg[opbase + tid] = tot;
    }
    __syncthreads();
  }
}

// ---------------- kernel 3: out = merge(Opart)/denom @ wo + bo — MFMA (frozen R16) ----------------
__global__ __launch_bounds__(256, 1) void out_kernel(
    const float* __restrict__ OPg, const float* __restrict__ PSg,
    const __hip_bfloat16* __restrict__ WOBH, const __hip_bfloat16* __restrict__ WOBL,
    const float* __restrict__ bo, float* __restrict__ out)
{
  __shared__ __align__(16) __hip_bfloat16 apH[8192];   // [kc][lane][8]
  __shared__ __align__(16) __hip_bfloat16 apL[8192];
  __shared__ float invs[16][8];

  const int tid  = threadIdx.x;
  const int b    = blockIdx.x >> 6;
  const int n0   = (blockIdx.x & 63) << 4;
  const int lane = tid & 63;
  const int wave = tid >> 6;

  if (tid < 128) {
    const int r = tid >> 3, h = tid & 7;
    const size_t row = (size_t)b * SEQ + h * NSEQ + n0 + r;
    invs[r][h] = 1.0f / (PSg[row] + PSg[(size_t)B_ * SEQ + row]);
  }
  __syncthreads();

  // ---- phase 1: merge halves + normalize -> hi/lo A-frag pack.
  {
    const int m   = tid & 15;
    const int q   = (tid >> 4) & 3;
    const int kc0 = tid >> 6;
    #pragma unroll
    for (int pss = 0; pss < 4; ++pss) {
      const int kc = kc0 + pss * 4;
      const int h  = kc >> 1;
      const int dh = (q + 4 * (kc & 1)) * 8;
      const size_t idx = (((size_t)b * H_ + h) * NSEQ + n0 + m) * DH + dh;
      const float4 a0 = *(const float4*)(OPg + idx);
      const float4 a1 = *(const float4*)(OPg + idx + 4);
      const float4 b0 = *(const float4*)(OPg + OPHALF + idx);
      const float4 b1 = *(const float4*)(OPg + OPHALF + idx + 4);
      const float inv = invs[m][h];
      float v[8];
      v[0] = (a0.x + b0.x) * inv; v[1] = (a0.y + b0.y) * inv;
      v[2] = (a0.z + b0.z) * inv; v[3] = (a0.w + b0.w) * inv;
      v[4] = (a1.x + b1.x) * inv; v[5] = (a1.y + b1.y) * inv;
      v[6] = (a1.z + b1.z) * inv; v[7] = (a1.w + b1.w) * inv;
      bf16x8 hv, lv;
      #pragma unroll
      for (int j = 0; j < 8; ++j) {
        const __bf16 h16 = (__bf16)v[j];
        hv[j] = h16;
        lv[j] = (__bf16)(v[j] - (float)h16);
      }
      const int off = (kc * 64 + (m + 16 * q)) * 8;
      *(bf16x8*)(apH + off) = hv;
      *(bf16x8*)(apL + off) = lv;
    }
  }
  __syncthreads();

  // ---- phase 2: MFMA. A-frags (all 16 kc, hi+lo) -> 128 VGPR, B from L2.
  bf16x8 ah[16], al[16];
  #pragma unroll
  for (int kc = 0; kc < 16; ++kc) {
    ah[kc] = *(const bf16x8*)(apH + (kc * 64 + lane) * 8);
    al[kc] = *(const bf16x8*)(apL + (kc * 64 + lane) * 8);
  }

  const int colq = lane & 15;
  const int quad = lane >> 4;

  #pragma unroll
  for (int nt4 = 0; nt4 < 4; ++nt4) {
    const int nt = nt4 * 4 + wave;
    const __hip_bfloat16* wbh = WOBH + ((size_t)nt * 16 * 64 + lane) * 8;
    const __hip_bfloat16* wbl = WOBL + ((size_t)nt * 16 * 64 + lane) * 8;
    floatx4 aHH = (floatx4){0.f, 0.f, 0.f, 0.f};
    floatx4 aHL = (floatx4){0.f, 0.f, 0.f, 0.f};
    floatx4 aLH = (floatx4){0.f, 0.f, 0.f, 0.f};
    #pragma unroll
    for (int kg = 0; kg < 4; ++kg) {
      bf16x8 bh[4], bl[4];
      #pragma unroll
      for (int j = 0; j < 4; ++j) {
        bh[j] = *(const bf16x8*)(wbh + (kg * 4 + j) * 512);
        bl[j] = *(const bf16x8*)(wbl + (kg * 4 + j) * 512);
      }
      #pragma unroll
      for (int j = 0; j < 4; ++j) {
        const int kc = kg * 4 + j;
        aHH = __builtin_amdgcn_mfma_f32_16x16x32_bf16(ah[kc], bh[j], aHH, 0, 0, 0);
        aHL = __builtin_amdgcn_mfma_f32_16x16x32_bf16(ah[kc], bl[j], aHL, 0, 0, 0);
        aLH = __builtin_amdgcn_mfma_f32_16x16x32_bf16(al[kc], bh[j], aLH, 0, 0, 0);
      }
    }
    const int n  = nt * 16 + colq;
    const float bv = bo[n];
    #pragma unroll
    for (int r = 0; r < 4; ++r) {
      const int mm = quad * 4 + r;
      out[((size_t)b * NSEQ + n0 + mm) * QS + n] =
          ((aHH[r] + aHL[r]) + aLH[r]) + bv;
    }
  }
}

extern "C" void kernel_launch(void* const* d_in, const int* in_sizes, int n_in,
                              void* d_out, int out_size, void* d_ws, size_t ws_size,
                              hipStream_t stream) {
  const float* x   = (const float*)d_in[0];
  const float* wq1 = (const float*)d_in[1];
  const float* wq2 = (const float*)d_in[2];
  const float* wk1 = (const float*)d_in[3];
  const float* wk2 = (const float*)d_in[4];
  const float* wv1 = (const float*)d_in[5];
  const float* wv2 = (const float*)d_in[6];
  const float* wo  = (const float*)d_in[7];
  const float* bo  = (const float*)d_in[8];
  float* out = (float*)d_out;

  __hip_bfloat16* Qg  = (__hip_bfloat16*)d_ws;
  __hip_bfloat16* KSg = Qg + (size_t)B_ * SEQ * DH;
  __hip_bfloat16* VSg = KSg + (size_t)B_ * KVSW_BATCH;
  float*          OPg = (float*)(VSg + (size_t)B_ * KVSW_BATCH);   // [2][B_][SEQ][DH]
  float*          PSg = OPg + 2 * (size_t)B_ * SEQ * DH;           // [2][B_][SEQ]
  __hip_bfloat16* WOBH = (__hip_bfloat16*)(PSg + 2 * (size_t)B_ * SEQ);
  __hip_bfloat16* WOBL = WOBH + (size_t)INNER * QS;                // 131072
  __hip_bfloat16* W1BH = WOBL + (size_t)INNER * QS;
  __hip_bfloat16* W1BL = W1BH + 32768;
  __hip_bfloat16* W2BH = W1BL + 32768;
  __hip_bfloat16* W2BL = W2BH + 98304;

  conv_kernel<<<80, 256, 0, stream>>>(wq1, wk1, wv1, wq2, wk2, wv2, wo,
                                      W1BH, W1BL, W2BH, W2BL, WOBH, WOBL);
  qkv_kernel<<<256, 512, 0, stream>>>(x, W1BH, W1BL, W2BH, W2BL, Qg, KSg, VSg);
  attn_kernel<<<1024, 256, 0, stream>>>(Qg, KSg, VSg, OPg, PSg);
  out_kernel<<<256, 256, 0, stream>>>(OPg, PSg, WOBH, WOBL, bo, out);
}

// Round 11
// 166.734 us; speedup vs baseline: 1.0900x; 1.0002x over previous
//
#include <hip/hip_runtime.h>
#include <hip/hip_bf16.h>

// CrossAttention: b=4, n=1024, qs=256, heads=8, dim_head=64, bottleneck=40.
// Attention = full 8192x8192 softmax-attention per batch over D=64.
//
// R24: R23 (verified 166.8us baseline) + ONE change in attn:
//   __launch_bounds__(256,3) -> (256,2) and pair-loop unroll 2 -> 4.
//   Rationale: occupancy is granule-pinned at 2 waves/SIMD (148->256
//   bucket) regardless of the bound, so the old ~170-reg cap only starved
//   the compiler's software pipeliner. 256-reg headroom allows 3-4
//   PairBufs in flight (4x32 + qf 32 + oacc 64 ~ 240 regs, no spill).
//   Tripwires: Occupancy <20% or WRITE >> 16.6MB = revert; VGPR ~84
//   unchanged = compiler ignored headroom = null, declare plateau.
//  - conv/qkv/out: frozen (R17/R16 forms).
//
// Workspace: Q|K_sw|V_sw 12MB | Opart 16MB | psum 256KB | WOB 512KB |
//            W1B 128KB | W2B 384KB ~ 29.3MB.

#define B_    4
#define H_    8
#define NSEQ  1024
#define SEQ   8192        // H_*NSEQ
#define DH    64
#define QS    256
#define INNER 512
#define QSCALE 0.18033688011112042f   // (1/sqrt(64)) * log2(e)

#define KVSW_BATCH 524288             // elems per batch in K_sw / V_sw
#define OPHALF (2097152)              // B_*SEQ*DH

typedef __bf16 bf16x8 __attribute__((ext_vector_type(8)));
typedef float floatx4 __attribute__((ext_vector_type(4)));

// ---------------- kernel 0: weight -> bf16 hi/lo fragment conversion ----------------
// grid 80, 256 thr. blocks [0,16): w1cat (256x128, cols 120-127 zero);
// [16,64): w2 per proj (K 40->64 zero-pad, N=512); [64,80): wo.
__global__ __launch_bounds__(256) void conv_kernel(
    const float* __restrict__ wq1, const float* __restrict__ wk1,
    const float* __restrict__ wv1,
    const float* __restrict__ wq2, const float* __restrict__ wk2,
    const float* __restrict__ wv2,
    const float* __restrict__ wo,
    __hip_bfloat16* __restrict__ W1BH, __hip_bfloat16* __restrict__ W1BL,
    __hip_bfloat16* __restrict__ W2BH, __hip_bfloat16* __restrict__ W2BL,
    __hip_bfloat16* __restrict__ WOBH, __hip_bfloat16* __restrict__ WOBL)
{
  const int tid = threadIdx.x;
  const int blk = blockIdx.x;

  if (blk < 16) {
    // ---- W1B: task t -> n = t&127, kq = t>>7 (kc = kq>>2, q = kq&3)
    const int t  = blk * 256 + tid;
    const int n  = t & 127;
    const int kq = t >> 7;
    const int kc = kq >> 2, q = kq & 3;
    const float* src; int col;
    if (n < 40)       { src = wq1; col = n; }
    else if (n < 80)  { src = wk1; col = n - 40; }
    else if (n < 120) { src = wv1; col = n - 80; }
    else              { src = nullptr; col = 0; }
    bf16x8 hv, lv;
    #pragma unroll
    for (int j = 0; j < 8; ++j) {
      const int k = kc * 32 + q * 8 + j;
      const float v = src ? src[k * 40 + col] : 0.f;
      const __bf16 h16 = (__bf16)v;
      hv[j] = h16; lv[j] = (__bf16)(v - (float)h16);
    }
    const size_t off = (((size_t)(n >> 4) * 8 + kc) * 64 + (n & 15) + 16 * q) * 8;
    *(bf16x8*)(W1BH + off) = hv;
    *(bf16x8*)(W1BL + off) = lv;
  } else if (blk < 64) {
    // ---- W2B: task t -> n = t&511, r = t>>9 (p = r>>3, kc = (r>>2)&1, q = r&3)
    const int t  = (blk - 16) * 256 + tid;
    const int n  = t & 511;
    const int r  = t >> 9;                    // [0,24)
    const int p  = r >> 3;
    const int kq = r & 7;
    const int kc = kq >> 2, q = kq & 3;
    const float* w2 = (p == 0) ? wq2 : (p == 1) ? wk2 : wv2;
    bf16x8 hv, lv;
    #pragma unroll
    for (int j = 0; j < 8; ++j) {
      const int k = kc * 32 + q * 8 + j;
      const float v = (k < 40) ? w2[(size_t)k * 512 + n] : 0.f;
      const __bf16 h16 = (__bf16)v;
      hv[j] = h16; lv[j] = (__bf16)(v - (float)h16);
    }
    const size_t off = ((((size_t)p * 32 + (n >> 4)) * 2 + kc) * 64 + (n & 15) + 16 * q) * 8;
    *(bf16x8*)(W2BH + off) = hv;
    *(bf16x8*)(W2BL + off) = lv;
  } else {
    // ---- WOB: harness-verified fragment conversion (R16 math).
    const int cid = blk - 64;                 // [0,16)
    const int t4  = (cid * 256 + tid) * 4;
    const int n   = t4 & 255;
    const int k8  = t4 >> 8;
    float4 rr[8];
    #pragma unroll
    for (int kk = 0; kk < 8; ++kk)
      rr[kk] = *(const float4*)(wo + (size_t)(k8 * 8 + kk) * QS + n);
    const int kc = k8 >> 2, qq = k8 & 3;
    #pragma unroll
    for (int nn = 0; nn < 4; ++nn) {
      const int nc = n + nn;
      const int l  = (nc & 15) + 16 * qq;
      const size_t off = ((size_t)((nc >> 4) * 16 + kc) * 64 + l) * 8;
      bf16x8 hv, lv;
      #pragma unroll
      for (int kk = 0; kk < 8; ++kk) {
        const float v = (nn == 0) ? rr[kk].x : (nn == 1) ? rr[kk].y
                      : (nn == 2) ? rr[kk].z : rr[kk].w;
        const __bf16 h16 = (__bf16)v;
        hv[kk] = h16;
        lv[kk] = (__bf16)(v - (float)h16);
      }
      *(bf16x8*)(WOBH + off) = hv;
      *(bf16x8*)(WOBL + off) = lv;
    }
  }
}

// ---------------- kernel 1: QKV projections, MFMA (frozen R17) ----------------
// grid 256 (b*64 + nblk), 512 thr (8 waves), 16 x-rows per block, all 3 proj.
__global__ __launch_bounds__(512) void qkv_kernel(
    const float* __restrict__ x,
    const __hip_bfloat16* __restrict__ W1BH, const __hip_bfloat16* __restrict__ W1BL,
    const __hip_bfloat16* __restrict__ W2BH, const __hip_bfloat16* __restrict__ W2BL,
    __hip_bfloat16* __restrict__ Qg, __hip_bfloat16* __restrict__ KSg,
    __hip_bfloat16* __restrict__ VSg)
{
  const int tid  = threadIdx.x;
  const int b    = blockIdx.x >> 6;
  const int nblk = blockIdx.x & 63;
  const int n0   = nblk << 4;
  const int wave = tid >> 6;
  const int lane = tid & 63;
  const int m    = lane & 15;     // A-frag row / D col-part
  const int q    = lane >> 4;     // k-subgroup / D row-quad

  __shared__ __align__(16) float xs[16][260];
  __shared__ __align__(16) float tb32[16][140];
  __shared__ __align__(16) __hip_bfloat16 qb[8320];    // [16][520]
  __shared__ __align__(16) __hip_bfloat16 kb[8320];    // [16][520]
  __shared__ __align__(16) __hip_bfloat16 vb[10240];   // [512][20]

  #pragma unroll
  for (int j = 0; j < 2; ++j) {
    const int i  = tid + j * 512;
    const int r  = i >> 6;
    const int c4 = (i & 63) << 2;
    *(float4*)(&xs[r][c4]) =
        *(const float4*)(x + ((size_t)b * NSEQ + n0 + r) * QS + c4);
  }
  __syncthreads();

  // ---- build x A-frags (hi/lo), all 8 K-chunks: row m, k = kc*32+q*8+j
  bf16x8 xh[8], xl[8];
  #pragma unroll
  for (int kc = 0; kc < 8; ++kc) {
    const float4 f0 = *(const float4*)(&xs[m][kc * 32 + q * 8]);
    const float4 f1 = *(const float4*)(&xs[m][kc * 32 + q * 8 + 4]);
    float v[8] = {f0.x, f0.y, f0.z, f0.w, f1.x, f1.y, f1.z, f1.w};
    #pragma unroll
    for (int j = 0; j < 8; ++j) {
      const __bf16 h16 = (__bf16)v[j];
      xh[kc][j] = h16;
      xl[kc][j] = (__bf16)(v[j] - (float)h16);
    }
  }

  // ---- stage 1: wave w owns cat n-tile w. 24 MFMA (3-chain hi/lo).
  {
    floatx4 hh = (floatx4){0.f, 0.f, 0.f, 0.f};
    floatx4 hl = (floatx4){0.f, 0.f, 0.f, 0.f};
    floatx4 lh = (floatx4){0.f, 0.f, 0.f, 0.f};
    const __hip_bfloat16* w1h = W1BH + ((size_t)wave * 8 * 64 + lane) * 8;
    const __hip_bfloat16* w1l = W1BL + ((size_t)wave * 8 * 64 + lane) * 8;
    #pragma unroll
    for (int kc = 0; kc < 8; ++kc) {
      const bf16x8 bh = *(const bf16x8*)(w1h + kc * 512);
      const bf16x8 bl = *(const bf16x8*)(w1l + kc * 512);
      hh = __builtin_amdgcn_mfma_f32_16x16x32_bf16(xh[kc], bh, hh, 0, 0, 0);
      hl = __builtin_amdgcn_mfma_f32_16x16x32_bf16(xh[kc], bl, hl, 0, 0, 0);
      lh = __builtin_amdgcn_mfma_f32_16x16x32_bf16(xl[kc], bh, lh, 0, 0, 0);
    }
    const int n1 = wave * 16 + m;   // cat col (D col = lane&15)
    #pragma unroll
    for (int r = 0; r < 4; ++r) {
      float d = (hh[r] + hl[r]) + lh[r];
      if (n1 >= 40 && n1 < 80) d = d / (1.f + __expf(-d));   // SiLU on K path
      tb32[q * 4 + r][n1] = d;       // D row = q*4+r
    }
  }
  __syncthreads();

  // ---- stage 2: per proj p (compile-time), wave covers n-tiles wave*4+i.
  #pragma unroll
  for (int p = 0; p < 3; ++p) {
    bf16x8 a2h[2], a2l[2];
    {
      const float4 g0 = *(const float4*)(&tb32[m][p * 40 + q * 8]);
      const float4 g1 = *(const float4*)(&tb32[m][p * 40 + q * 8 + 4]);
      float v[8] = {g0.x, g0.y, g0.z, g0.w, g1.x, g1.y, g1.z, g1.w};
      #pragma unroll
      for (int j = 0; j < 8; ++j) {
        const __bf16 h16 = (__bf16)v[j];
        a2h[0][j] = h16;
        a2l[0][j] = (__bf16)(v[j] - (float)h16);
      }
    }
    if (q == 0) {
      const float4 g0 = *(const float4*)(&tb32[m][p * 40 + 32]);
      const float4 g1 = *(const float4*)(&tb32[m][p * 40 + 36]);
      float v[8] = {g0.x, g0.y, g0.z, g0.w, g1.x, g1.y, g1.z, g1.w};
      #pragma unroll
      for (int j = 0; j < 8; ++j) {
        const __bf16 h16 = (__bf16)v[j];
        a2h[1][j] = h16;
        a2l[1][j] = (__bf16)(v[j] - (float)h16);
      }
    } else {
      #pragma unroll
      for (int j = 0; j < 8; ++j) { a2h[1][j] = (__bf16)0.f; a2l[1][j] = (__bf16)0.f; }
    }

    #pragma unroll
    for (int i = 0; i < 4; ++i) {
      const int nt = wave * 4 + i;
      floatx4 sHH = (floatx4){0.f, 0.f, 0.f, 0.f};
      floatx4 sHL = (floatx4){0.f, 0.f, 0.f, 0.f};
      floatx4 sLH = (floatx4){0.f, 0.f, 0.f, 0.f};
      #pragma unroll
      for (int kc = 0; kc < 2; ++kc) {
        const size_t boff = (((size_t)(p * 32 + nt) * 2 + kc) * 64 + lane) * 8;
        const bf16x8 bh = *(const bf16x8*)(W2BH + boff);
        const bf16x8 bl = *(const bf16x8*)(W2BL + boff);
        sHH = __builtin_amdgcn_mfma_f32_16x16x32_bf16(a2h[kc], bh, sHH, 0, 0, 0);
        sHL = __builtin_amdgcn_mfma_f32_16x16x32_bf16(a2h[kc], bl, sHL, 0, 0, 0);
        sLH = __builtin_amdgcn_mfma_f32_16x16x32_bf16(a2l[kc], bh, sLH, 0, 0, 0);
      }
      const int nn = nt * 16 + m;    // output col [0,512)
      #pragma unroll
      for (int r = 0; r < 4; ++r) {
        const int row = q * 4 + r;
        const float d = (sHH[r] + sHL[r]) + sLH[r];
        if (p == 0)      qb[row * 520 + nn] = __float2bfloat16(d * QSCALE);
        else if (p == 1) kb[row * 520 + nn] = __float2bfloat16(d);
        else             vb[nn * 20 + row]  = __float2bfloat16(d);
      }
    }
  }
  __syncthreads();

  // ---- Q write: 1024 float4 tasks, 2 per thread ----
  #pragma unroll
  for (int j = 0; j < 2; ++j) {
    const int i  = tid + j * 512;
    const int h  = i >> 7;
    const int r  = (i >> 3) & 15;
    const int d8 = i & 7;
    *(float4*)(Qg + ((size_t)b * SEQ + h * NSEQ + n0 + r) * DH + d8 * 8) =
        *(const float4*)(&qb[r * 520 + h * 64 + d8 * 8]);
  }
  // ---- K_sw write: 1024 float4 tasks, 2 per thread ----
  #pragma unroll
  for (int j = 0; j < 2; ++j) {
    const int i    = tid + j * 512;
    const int h    = i >> 7;
    const int ks2  = (i >> 6) & 1;
    const int quad = (i >> 4) & 3;
    const int r    = i & 15;
    const int ln   = quad * 16 + r;
    const size_t dst = (size_t)b * KVSW_BATCH
        + ((size_t)((h * 64 + nblk) * 2 + ks2) * 64 + ln) * 8;
    *(float4*)(KSg + dst) = *(const float4*)(&kb[r * 520 + h * 64 + ks2 * 32 + quad * 8]);
  }
  // ---- V_sw write: 2048 uint2 tasks, 4 per thread ----
  {
    const int st  = nblk & 1;
    const int p32 = nblk >> 1;
    #pragma unroll
    for (int pass = 0; pass < 4; ++pass) {
      const int i   = tid + pass * 512;
      const int h   = i >> 8;
      const int dnt = (i >> 6) & 3;
      const int dm  = (i >> 2) & 15;
      const int rg  = i & 3;
      const int ln  = rg * 16 + dm;
      const size_t dst = (size_t)b * KVSW_BATCH
          + ((size_t)((h * 32 + p32) * 4 + dnt) * 64 + ln) * 8 + st * 4;
      *(uint2*)(VSg + dst) = *(const uint2*)(&vb[(h * 64 + dnt * 16 + dm) * 20 + rg * 4]);
    }
  }
}

// ---------------- kernel 2: attention (R13 body; relaxed reg cap + unroll 4) ----------------
struct PairBuf {
  bf16x8 k[2][2];   // [strip][k-span]
  bf16x8 v[4];      // [d-tile]
};

__global__ __launch_bounds__(256, 2) void attn_kernel(
    const __hip_bfloat16* __restrict__ Qg,
    const __hip_bfloat16* __restrict__ KSg,
    const __hip_bfloat16* __restrict__ VSg,
    float* __restrict__ OPg,       // [2][B_][SEQ][DH]
    float* __restrict__ PSg)       // [2][B_][SEQ]
{
  __shared__ float Osh[4][16][68];
  __shared__ float psums[4][64];

  const int tid  = threadIdx.x;
  const int wave = tid >> 6;
  const int lane = tid & 63;
  const int lrow = lane & 15;
  const int quad = lane >> 4;

  const int xcd   = blockIdx.x & 7;
  const int idx   = blockIdx.x >> 3;       // [0,128)
  const int b     = xcd >> 1;
  const int half  = idx & 1;
  const int qtile = (xcd & 1) * 64 + (idx >> 1);
  const int qbase = qtile * 64;

  const __hip_bfloat16* Qb  = Qg + ((size_t)b * SEQ + qbase) * DH;
  const __hip_bfloat16* kp0 = KSg + (size_t)b * KVSW_BATCH + half * 262144
                              + (size_t)wave * 65536 + lane * 8;
  const __hip_bfloat16* vp0 = VSg + (size_t)b * KVSW_BATCH + half * 262144
                              + (size_t)wave * 65536 + lane * 8;

  bf16x8 qf[4][2];
  #pragma unroll
  for (int mt = 0; mt < 4; ++mt)
    #pragma unroll
    for (int s = 0; s < 2; ++s)
      qf[mt][s] = *(const bf16x8*)(Qb + (mt * 16 + lrow) * DH + s * 32 + quad * 8);

  floatx4 oacc[4][4];   // [mt][dnt] — 64 acc regs (unified budget)
  #pragma unroll
  for (int mt = 0; mt < 4; ++mt)
    #pragma unroll
    for (int dnt = 0; dnt < 4; ++dnt)
      oacc[mt][dnt] = (floatx4){0.f, 0.f, 0.f, 0.f};
  float psum[4] = {0.f, 0.f, 0.f, 0.f};

  #pragma unroll 4
  for (int pair = 0; pair < 32; ++pair) {
    PairBuf pb;
    const __hip_bfloat16* kp = kp0 + pair * 2048;
    pb.k[0][0] = *(const bf16x8*)(kp);
    pb.k[0][1] = *(const bf16x8*)(kp + 512);
    pb.k[1][0] = *(const bf16x8*)(kp + 1024);
    pb.k[1][1] = *(const bf16x8*)(kp + 1536);
    const __hip_bfloat16* vp = vp0 + pair * 2048;
    #pragma unroll
    for (int dnt = 0; dnt < 4; ++dnt)
      pb.v[dnt] = *(const bf16x8*)(vp + dnt * 512);

    #pragma unroll
    for (int mt = 0; mt < 4; ++mt) {
      floatx4 s0 = (floatx4){0.f, 0.f, 0.f, 0.f};
      floatx4 s1 = (floatx4){0.f, 0.f, 0.f, 0.f};
      s0 = __builtin_amdgcn_mfma_f32_16x16x32_bf16(pb.k[0][0], qf[mt][0], s0, 0, 0, 0);
      s0 = __builtin_amdgcn_mfma_f32_16x16x32_bf16(pb.k[0][1], qf[mt][1], s0, 0, 0, 0);
      s1 = __builtin_amdgcn_mfma_f32_16x16x32_bf16(pb.k[1][0], qf[mt][0], s1, 0, 0, 0);
      s1 = __builtin_amdgcn_mfma_f32_16x16x32_bf16(pb.k[1][1], qf[mt][1], s1, 0, 0, 0);
      float p[8];
      #pragma unroll
      for (int r = 0; r < 4; ++r) {
        p[r]     = __builtin_amdgcn_exp2f(s0[r]);
        p[4 + r] = __builtin_amdgcn_exp2f(s1[r]);
      }
      psum[mt] += ((p[0] + p[1]) + (p[2] + p[3])) + ((p[4] + p[5]) + (p[6] + p[7]));
      bf16x8 pa;
      #pragma unroll
      for (int j = 0; j < 8; ++j) pa[j] = (__bf16)p[j];
      #pragma unroll
      for (int dnt = 0; dnt < 4; ++dnt)
        oacc[mt][dnt] = __builtin_amdgcn_mfma_f32_16x16x32_bf16(pa, pb.v[dnt], oacc[mt][dnt], 0, 0, 0);
    }
  }

  #pragma unroll
  for (int mt = 0; mt < 4; ++mt) {
    float s = psum[mt];
    s += __shfl_xor(s, 16, 64);
    s += __shfl_xor(s, 32, 64);
    psum[mt] = s;
  }
  if (quad == 0) {
    #pragma unroll
    for (int mt = 0; mt < 4; ++mt)
      psums[wave][mt * 16 + lrow] = psum[mt];
  }

  const size_t opbase = ((size_t)half * B_ + b) * SEQ + qbase;

  #pragma unroll
  for (int mt = 0; mt < 4; ++mt) {
    #pragma unroll
    for (int dnt = 0; dnt < 4; ++dnt)
      #pragma unroll
      for (int r = 0; r < 4; ++r)
        Osh[wave][quad * 4 + r][dnt * 16 + lrow] = oacc[mt][dnt][r];
    __syncthreads();

    {
      const int q16 = tid >> 4;
      const int d0  = (tid & 15) * 4;
      float4 a0 = *(const float4*)(&Osh[0][q16][d0]);
      float4 a1 = *(const float4*)(&Osh[1][q16][d0]);
      float4 a2 = *(const float4*)(&Osh[2][q16][d0]);
      float4 a3 = *(const float4*)(&Osh[3][q16][d0]);
      float4 res;
      res.x = (a0.x + a1.x) + (a2.x + a3.x);
      res.y = (a0.y + a1.y) + (a2.y + a3.y);
      res.z = (a0.z + a1.z) + (a2.z + a3.z);
      res.w = (a0.w + a1.w) + (a2.w + a3.w);
      *(float4*)(OPg + (opbase + mt * 16 + q16) * DH + d0) = res;
    }
    if (mt == 0 && tid < 64) {
      const float tot = (psums[0][tid] + psums[1][tid]) + (psums[2][tid] + psums[3][tid]);
      PSg[opbase + tid] = tot;
    }
    __syncthreads();
  }
}

// ---------------- kernel 3: out = merge(Opart)/denom @ wo + bo — MFMA (frozen R16) ----------------
__global__ __launch_bounds__(256, 1) void out_kernel(
    const float* __restrict__ OPg, const float* __restrict__ PSg,
    const __hip_bfloat16* __restrict__ WOBH, const __hip_bfloat16* __restrict__ WOBL,
    const float* __restrict__ bo, float* __restrict__ out)
{
  __shared__ __align__(16) __hip_bfloat16 apH[8192];   // [kc][lane][8]
  __shared__ __align__(16) __hip_bfloat16 apL[8192];
  __shared__ float invs[16][8];

  const int tid  = threadIdx.x;
  const int b    = blockIdx.x >> 6;
  const int n0   = (blockIdx.x & 63) << 4;
  const int lane = tid & 63;
  const int wave = tid >> 6;

  if (tid < 128) {
    const int r = tid >> 3, h = tid & 7;
    const size_t row = (size_t)b * SEQ + h * NSEQ + n0 + r;
    invs[r][h] = 1.0f / (PSg[row] + PSg[(size_t)B_ * SEQ + row]);
  }
  __syncthreads();

  // ---- phase 1: merge halves + normalize -> hi/lo A-frag pack.
  {
    const int m   = tid & 15;
    const int q   = (tid >> 4) & 3;
    const int kc0 = tid >> 6;
    #pragma unroll
    for (int pss = 0; pss < 4; ++pss) {
      const int kc = kc0 + pss * 4;
      const int h  = kc >> 1;
      const int dh = (q + 4 * (kc & 1)) * 8;
      const size_t idx = (((size_t)b * H_ + h) * NSEQ + n0 + m) * DH + dh;
      const float4 a0 = *(const float4*)(OPg + idx);
      const float4 a1 = *(const float4*)(OPg + idx + 4);
      const float4 b0 = *(const float4*)(OPg + OPHALF + idx);
      const float4 b1 = *(const float4*)(OPg + OPHALF + idx + 4);
      const float inv = invs[m][h];
      float v[8];
      v[0] = (a0.x + b0.x) * inv; v[1] = (a0.y + b0.y) * inv;
      v[2] = (a0.z + b0.z) * inv; v[3] = (a0.w + b0.w) * inv;
      v[4] = (a1.x + b1.x) * inv; v[5] = (a1.y + b1.y) * inv;
      v[6] = (a1.z + b1.z) * inv; v[7] = (a1.w + b1.w) * inv;
      bf16x8 hv, lv;
      #pragma unroll
      for (int j = 0; j < 8; ++j) {
        const __bf16 h16 = (__bf16)v[j];
        hv[j] = h16;
        lv[j] = (__bf16)(v[j] - (float)h16);
      }
      const int off = (kc * 64 + (m + 16 * q)) * 8;
      *(bf16x8*)(apH + off) = hv;
      *(bf16x8*)(apL + off) = lv;
    }
  }
  __syncthreads();

  // ---- phase 2: MFMA. A-frags (all 16 kc, hi+lo) -> 128 VGPR, B from L2.
  bf16x8 ah[16], al[16];
  #pragma unroll
  for (int kc = 0; kc < 16; ++kc) {
    ah[kc] = *(const bf16x8*)(apH + (kc * 64 + lane) * 8);
    al[kc] = *(const bf16x8*)(apL + (kc * 64 + lane) * 8);
  }

  const int colq = lane & 15;
  const int quad = lane >> 4;

  #pragma unroll
  for (int nt4 = 0; nt4 < 4; ++nt4) {
    const int nt = nt4 * 4 + wave;
    const __hip_bfloat16* wbh = WOBH + ((size_t)nt * 16 * 64 + lane) * 8;
    const __hip_bfloat16* wbl = WOBL + ((size_t)nt * 16 * 64 + lane) * 8;
    floatx4 aHH = (floatx4){0.f, 0.f, 0.f, 0.f};
    floatx4 aHL = (floatx4){0.f, 0.f, 0.f, 0.f};
    floatx4 aLH = (floatx4){0.f, 0.f, 0.f, 0.f};
    #pragma unroll
    for (int kg = 0; kg < 4; ++kg) {
      bf16x8 bh[4], bl[4];
      #pragma unroll
      for (int j = 0; j < 4; ++j) {
        bh[j] = *(const bf16x8*)(wbh + (kg * 4 + j) * 512);
        bl[j] = *(const bf16x8*)(wbl + (kg * 4 + j) * 512);
      }
      #pragma unroll
      for (int j = 0; j < 4; ++j) {
        const int kc = kg * 4 + j;
        aHH = __builtin_amdgcn_mfma_f32_16x16x32_bf16(ah[kc], bh[j], aHH, 0, 0, 0);
        aHL = __builtin_amdgcn_mfma_f32_16x16x32_bf16(ah[kc], bl[j], aHL, 0, 0, 0);
        aLH = __builtin_amdgcn_mfma_f32_16x16x32_bf16(al[kc], bh[j], aLH, 0, 0, 0);
      }
    }
    const int n  = nt * 16 + colq;
    const float bv = bo[n];
    #pragma unroll
    for (int r = 0; r < 4; ++r) {
      const int mm = quad * 4 + r;
      out[((size_t)b * NSEQ + n0 + mm) * QS + n] =
          ((aHH[r] + aHL[r]) + aLH[r]) + bv;
    }
  }
}

extern "C" void kernel_launch(void* const* d_in, const int* in_sizes, int n_in,
                              void* d_out, int out_size, void* d_ws, size_t ws_size,
                              hipStream_t stream) {
  const float* x   = (const float*)d_in[0];
  const float* wq1 = (const float*)d_in[1];
  const float* wq2 = (const float*)d_in[2];
  const float* wk1 = (const float*)d_in[3];
  const float* wk2 = (const float*)d_in[4];
  const float* wv1 = (const float*)d_in[5];
  const float* wv2 = (const float*)d_in[6];
  const float* wo  = (const float*)d_in[7];
  const float* bo  = (const float*)d_in[8];
  float* out = (float*)d_out;

  __hip_bfloat16* Qg  = (__hip_bfloat16*)d_ws;
  __hip_bfloat16* KSg = Qg + (size_t)B_ * SEQ * DH;
  __hip_bfloat16* VSg = KSg + (size_t)B_ * KVSW_BATCH;
  float*          OPg = (float*)(VSg + (size_t)B_ * KVSW_BATCH);   // [2][B_][SEQ][DH]
  float*          PSg = OPg + 2 * (size_t)B_ * SEQ * DH;           // [2][B_][SEQ]
  __hip_bfloat16* WOBH = (__hip_bfloat16*)(PSg + 2 * (size_t)B_ * SEQ);
  __hip_bfloat16* WOBL = WOBH + (size_t)INNER * QS;                // 131072
  __hip_bfloat16* W1BH = WOBL + (size_t)INNER * QS;
  __hip_bfloat16* W1BL = W1BH + 32768;
  __hip_bfloat16* W2BH = W1BL + 32768;
  __hip_bfloat16* W2BL = W2BH + 98304;

  conv_kernel<<<80, 256, 0, stream>>>(wq1, wk1, wv1, wq2, wk2, wv2, wo,
                                      W1BH, W1BL, W2BH, W2BL, WOBH, WOBL);
  qkv_kernel<<<256, 512, 0, stream>>>(x, W1BH, W1BL, W2BH, W2BL, Qg, KSg, VSg);
  attn_kernel<<<1024, 256, 0, stream>>>(Qg, KSg, VSg, OPg, PSg);
  out_kernel<<<256, 256, 0, stream>>>(OPg, PSg, WOBH, WOBL, bo, out);
}